// Round 8
// baseline (1237.202 us; speedup 1.0000x reference)
//
#include <hip/hip_runtime.h>
#include <hip/hip_bf16.h>

// Problem constants (AKT core): B=16, S=512, D=512, H=8, DFF=2048, NB=2, L=6
#define Bsz  16
#define Sl   512
#define Dm   512
#define Hn   8
#define DKh  64
#define DFFn 2048
#define MROWS (Bsz * Sl)      // 8192
#define NEGV (-1e32f)

typedef _Float16 f16;
typedef f16 f16x8 __attribute__((ext_vector_type(8)));
typedef f16 f16x4 __attribute__((ext_vector_type(4)));
typedef float f32x4 __attribute__((ext_vector_type(4)));

// async global->LDS, 16B per lane: lds dst = wave-uniform base + lane*16
#define GLDS16(g, l) __builtin_amdgcn_global_load_lds( \
    (const __attribute__((address_space(1))) void*)(g), \
    (__attribute__((address_space(3))) void*)(l), 16, 0, 0)

// ---------------------------------------------------------------------------
// k_prep: all one-off preprocessing in ONE launch (fewer dispatch gaps).
// ---------------------------------------------------------------------------
struct PrepArgs {
    const float *Wk, *Wv, *Wo, *W1, *W2, *bk, *bv, *q_emb, *qa_emb;
    f16 *wkvh, *woh, *w1h, *w2h;
    float *bkv, *xbuf, *ybuf;
    f16 *xh, *yh;
};

__device__ __forceinline__ void wconv_body(const float* src, f16* dst,
        int K, int N, int lmap, size_t zstride, int z, int nx, int ny,
        int t, float (*T)[36])
{
    int ls = lmap ? (z < 2 ? z : 2 * z - 1) : z;
    const float* S = src + (size_t)ls * K * N;
    f16* Dt = dst + (size_t)z * zstride;
    int n0 = nx * 32, k0 = ny * 32;
    int r = t >> 3, c = (t & 7) * 4;
    float4 v = *(const float4*)(S + (size_t)(k0 + r) * N + n0 + c);
    T[r][c] = v.x; T[r][c + 1] = v.y; T[r][c + 2] = v.z; T[r][c + 3] = v.w;
    __syncthreads();
    int n = t >> 3, kq = (t & 7) * 4;
    f16x4 o = { (f16)T[kq][n], (f16)T[kq + 1][n], (f16)T[kq + 2][n], (f16)T[kq + 3][n] };
    *(f16x4*)(Dt + (size_t)(n0 + n) * K + k0 + kq) = o;
}

__global__ __launch_bounds__(256) void k_prep(PrepArgs a)
{
    __shared__ float T[32][36];
    int id = blockIdx.x;
    int t = threadIdx.x;
    const size_t WDD = (size_t)Dm * Dm;
    const size_t WDF = (size_t)Dm * DFFn;
    const size_t WKV = 2 * WDD;

    if (id < 4608) {
        int which = id / 1536, rest = id % 1536;
        int z = rest >> 8, r2 = rest & 255;
        int nx = r2 & 15, ny = r2 >> 4;
        if (which == 0)      wconv_body(a.Wk, a.wkvh,       Dm, Dm, 0, WKV, z, nx, ny, t, T);
        else if (which == 1) wconv_body(a.Wv, a.wkvh + WDD, Dm, Dm, 0, WKV, z, nx, ny, t, T);
        else                 wconv_body(a.Wo, a.woh,        Dm, Dm, 0, WDD, z, nx, ny, t, T);
    } else if (id < 8704) {
        int id2 = id - 4608;
        int z = id2 >> 10, r2 = id2 & 1023;
        int nx = r2 & 63, ny = r2 >> 6;          // N=2048: 64 x-tiles, 16 y
        wconv_body(a.W1, a.w1h, Dm, DFFn, 1, WDF, z, nx, ny, t, T);
    } else if (id < 12800) {
        int id3 = id - 8704;
        int z = id3 >> 10, r2 = id3 & 1023;
        int nx = r2 & 15, ny = r2 >> 4;          // K=2048: 16 x, 64 y
        wconv_body(a.W2, a.w2h, DFFn, Dm, 1, WDF, z, nx, ny, t, T);
    } else if (id < 12824) {
        int i = (id - 12800) * 256 + t;          // 6*1024
        int z = i >> 10, c = i & 1023;
        a.bkv[i] = (c < 512) ? a.bk[z * 512 + c] : a.bv[z * 512 + c - 512];
    } else if (id < 29208) {
        int i = (id - 12824) * 256 + t;
        float v = a.q_emb[i];
        a.xbuf[i] = v; a.xh[i] = (f16)v;
    } else {
        int i = (id - 29208) * 256 + t;
        float v = a.qa_emb[i];
        a.ybuf[i] = v; a.yh[i] = (f16)v;
    }
}

// ---------------------------------------------------------------------------
// MFMA f16 GEMM: C[M,N] = A[M,K] @ Bt[N,K]^T + bias[N]. A,Bt f16; bias f32.
// 128x128 tile, 4 waves, 16x16x32 MFMA, 4x4/wave.
// BK64 path: DEEP PIPELINE (T3+T4) — 3 LDS buffers, prefetch distance 2,
//   raw s_barrier + counted s_waitcnt vmcnt(8) (one STAGE = 8 GLDS16/wave;
//   never drain to 0 in the loop). Bias is preloaded and vmcnt(0)-drained
//   BEFORE staging so the counted waits see only staging loads.
//   96KB LDS -> 1 block/CU; used only on <=512-block grids.
// BK32 path (FFN1, 4 blocks/CU): old 2-buffer __syncthreads pipeline (TLP
//   already covers latency there).
// VTOUT=1: vt[bh][d][s] layout. VTOUT=2: fused KV N=1024. VTOUT=3: dual
//   independent projections (bx<4 -> qh, bx>=4 -> A2@Bt[512:] -> vt).
// ---------------------------------------------------------------------------
template <int RELU, int OUT16, int VTOUT, int BK64>
__global__ __launch_bounds__(256) void k_gemm(
    const f16* __restrict__ A, const f16* __restrict__ Bt,
    const float* __restrict__ bias, float* __restrict__ C, f16* __restrict__ Ch,
    int M, int N, int K,
    const f16* __restrict__ A2, f16* __restrict__ Ch2)
{
    constexpr int HL = BK64 ? 2 : 1;        // 32-wide halves per K-step
    constexpr int BUF = HL * 4096;          // f16 per buffer per matrix
    constexpr int NBUF = BK64 ? 3 : 2;
    __shared__ f16 As[NBUF * BUF];
    __shared__ f16 Bs[NBUF * BUF];
    int tid = threadIdx.x;
    int w = tid >> 6, lane = tid & 63;
    int ln = lane & 15, rg = lane >> 4;
    int wr = w >> 1, wc = w & 1;
    int m0 = blockIdx.y * 128;
    int half = (VTOUT == 3) ? (blockIdx.x >> 2) : 0;
    int n0 = (VTOUT == 3) ? (blockIdx.x & 3) * 128 : blockIdx.x * 128;

    const f16* Ause = (VTOUT == 3 && half) ? A2 : A;
    const f16* Btuse = (VTOUT == 3) ? Bt + (size_t)half * 512 * 512 : Bt;
    const float* biasuse = (VTOUT == 3) ? bias + half * 512 : bias;

    // bias preload: must complete before staging so counted vmcnt is exact
    float bj4[4];
#pragma unroll
    for (int j = 0; j < 4; ++j)
        bj4[j] = biasuse[n0 + wc * 64 + j * 16 + ln];
    if (BK64) asm volatile("s_waitcnt vmcnt(0)" ::: "memory");

    int s0 = tid, s1 = 256 + tid;
    int r0s = s0 >> 2, c0s = ((s0 & 3) ^ ((s0 >> 3) & 3));
    int r1s = s1 >> 2, c1s = ((s1 & 3) ^ ((s1 >> 3) & 3));

    const f16* a0 = Ause + (size_t)(m0 + r0s) * K + c0s * 8;
    const f16* a1 = Ause + (size_t)(m0 + r1s) * K + c1s * 8;
    const f16* b0 = Btuse + (size_t)(n0 + r0s) * K + c0s * 8;
    const f16* b1 = Btuse + (size_t)(n0 + r1s) * K + c1s * 8;

    int cc8 = (rg ^ ((ln >> 1) & 3)) * 8;

    f32x4 acc[4][4] = {};

    int nk = K >> (BK64 ? 6 : 5);

    auto STAGE = [&](int nb, int kt) {
        f16* lA = As + nb * BUF + w * 512;
        f16* lB = Bs + nb * BUF + w * 512;
        GLDS16(a0 + kt, lA);
        GLDS16(a1 + kt, lA + 2048);
        GLDS16(b0 + kt, lB);
        GLDS16(b1 + kt, lB + 2048);
        if (BK64) {
            GLDS16(a0 + kt + 32, lA + 4096);
            GLDS16(a1 + kt + 32, lA + 4096 + 2048);
            GLDS16(b0 + kt + 32, lB + 4096);
            GLDS16(b1 + kt + 32, lB + 4096 + 2048);
        }
    };

    auto COMPUTE = [&](int nb) {
#pragma unroll
        for (int hh = 0; hh < HL; ++hh) {
            const f16* Ab = As + nb * BUF + hh * 4096;
            const f16* Bb = Bs + nb * BUF + hh * 4096;
            f16x8 af[4], bf[4];
#pragma unroll
            for (int i = 0; i < 4; ++i) {
                int m = wr * 64 + i * 16 + ln;
                af[i] = *(const f16x8*)(Ab + m * 32 + cc8);
                int nn = wc * 64 + i * 16 + ln;
                bf[i] = *(const f16x8*)(Bb + nn * 32 + cc8);
            }
#pragma unroll
            for (int i = 0; i < 4; ++i)
#pragma unroll
                for (int j = 0; j < 4; ++j)
                    acc[i][j] = __builtin_amdgcn_mfma_f32_16x16x32_f16(af[i], bf[j], acc[i][j], 0, 0, 0);
        }
    };

    if (BK64) {
        // ---- deep pipeline: 3 buffers, prefetch distance 2, counted vmcnt
        STAGE(0, 0);
        STAGE(1, 64);
        asm volatile("s_waitcnt vmcnt(8)" ::: "memory");   // buf0 ready
        __builtin_amdgcn_s_barrier();
        int cur = 0;
        for (int t = 0; t < nk; ++t) {
            int nx = t + 2;
            if (nx < nk) STAGE(cur == 0 ? 2 : cur - 1, nx << 6);
            COMPUTE(cur);
            if (t + 1 < nk) {
                if (nx < nk) asm volatile("s_waitcnt vmcnt(8)" ::: "memory");
                else         asm volatile("s_waitcnt vmcnt(0)" ::: "memory");
                __builtin_amdgcn_s_barrier();
            }
            cur = (cur == 2) ? 0 : cur + 1;
        }
    } else {
        // ---- 2-buffer __syncthreads pipeline (multi-block/CU grids)
        STAGE(0, 0);
        __syncthreads();
        int cur = 0;
        for (int t = 0; t < nk; ++t) {
            if (t + 1 < nk) STAGE(cur ^ 1, (t + 1) << 5);
            COMPUTE(cur);
            __syncthreads();
            cur ^= 1;
        }
    }

#pragma unroll
    for (int j = 0; j < 4; ++j) {
        int col = n0 + wc * 64 + j * 16 + ln;
        float bj = bj4[j];
#pragma unroll
        for (int i = 0; i < 4; ++i) {
            int rb = m0 + wr * 64 + i * 16 + rg * 4;
            if (VTOUT == 1) {
                // vt[((b*8+h)*64 + dk)*512 + s], s = 4 consecutive rows
                int bq = rb >> 9, s = rb & 511;
                int hh = col >> 6, dk = col & 63;
                f16x4 o;
#pragma unroll
                for (int r = 0; r < 4; ++r) o[r] = (f16)(acc[i][j][r] + bj);
                *(f16x4*)(Ch + (((size_t)(bq * 8 + hh) * 64 + dk) << 9) + s) = o;
            } else if (VTOUT == 2) {
                if (n0 < 512) {       // qh half (block-uniform branch)
#pragma unroll
                    for (int r = 0; r < 4; ++r)
                        Ch[(size_t)(rb + r) * 512 + col] = (f16)(acc[i][j][r] + bj);
                } else {              // vt half
                    f16* Cv = (f16*)C;
                    int colv = col - 512;
                    int bq = rb >> 9, s = rb & 511;
                    int hh = colv >> 6, dk = colv & 63;
                    f16x4 o;
#pragma unroll
                    for (int r = 0; r < 4; ++r) o[r] = (f16)(acc[i][j][r] + bj);
                    *(f16x4*)(Cv + (((size_t)(bq * 8 + hh) * 64 + dk) << 9) + s) = o;
                }
            } else if (VTOUT == 3) {
                if (half == 0) {      // qh
#pragma unroll
                    for (int r = 0; r < 4; ++r)
                        Ch[(size_t)(rb + r) * 512 + col] = (f16)(acc[i][j][r] + bj);
                } else {              // vt
                    int bq = rb >> 9, s = rb & 511;
                    int hh = col >> 6, dk = col & 63;
                    f16x4 o;
#pragma unroll
                    for (int r = 0; r < 4; ++r) o[r] = (f16)(acc[i][j][r] + bj);
                    *(f16x4*)(Ch2 + (((size_t)(bq * 8 + hh) * 64 + dk) << 9) + s) = o;
                }
            } else {
#pragma unroll
                for (int r = 0; r < 4; ++r) {
                    float v = acc[i][j][r] + bj;
                    if (RELU) v = fmaxf(v, 0.f);
                    if (OUT16) Ch[(size_t)(rb + r) * N + col] = (f16)v;
                    else       C [(size_t)(rb + r) * N + col] = v;
                }
            }
        }
    }
}

// ---------------------------------------------------------------------------
// AKT attention body, specialized on JTC. Scores in registers after one
// vectorized LDS read; loop B LDS-free. (Unchanged from round 7.)
// ---------------------------------------------------------------------------
template <int JTC>
__device__ __forceinline__ void attn_body(
    float (*Sc)[516], f16* Ph, const f16* Qbase, const f16* vbase, f16* ob,
    f16x8 aq0, f16x8 aq1, float g,
    int w, int lane, int ln, int rg, int i0, int maskflag)
{
    // ---- Phase 1: scores, 16-col unit granularity across waves ----------
#pragma unroll
    for (int ui = 0; ui < JTC; ++ui) {
        int u = w + ui * 4;
        const f16* kb = Qbase + (size_t)(u * 16 + ln) * Dm + rg * 8;
        f16x8 b0 = *(const f16x8*)(kb);
        f16x8 b1 = *(const f16x8*)(kb + 32);
        f32x4 c = {};
        c = __builtin_amdgcn_mfma_f32_16x16x32_f16(aq0, b0, c, 0, 0, 0);
        c = __builtin_amdgcn_mfma_f32_16x16x32_f16(aq1, b1, c, 0, 0, 0);
#pragma unroll
        for (int r = 0; r < 4; ++r)
            Sc[rg * 4 + r][u * 16 + ln] = c[r];
    }
    __syncthreads();

    int jbase = lane * JTC;
    int im = i0 + w * 4;

    // ---- loop A: vector-read scores -> regs, mask+scale, first exp-sums -
    float ss[4][JTC];
    float run[4];
#pragma unroll
    for (int q = 0; q < 4; ++q) {
        const float* Srow = &Sc[w * 4 + q][0];
        if constexpr (JTC == 8) {
            float4 t0 = *(const float4*)(Srow + jbase);
            float4 t1 = *(const float4*)(Srow + jbase + 4);
            ss[q][0] = t0.x; ss[q][1] = t0.y; ss[q][2] = t0.z; ss[q][3] = t0.w;
            ss[q][4] = t1.x; ss[q][5] = t1.y; ss[q][6] = t1.z; ss[q][7] = t1.w;
        } else if constexpr (JTC == 4) {
            float4 t0 = *(const float4*)(Srow + jbase);
            ss[q][0] = t0.x; ss[q][1] = t0.y; ss[q][2] = t0.z; ss[q][3] = t0.w;
        } else {
#pragma unroll
            for (int k = 0; k < JTC; ++k) ss[q][k] = Srow[jbase + k];
        }
        int jmax = maskflag ? (im + q) : (im + q - 1);
        float acc = 0.f;
#pragma unroll
        for (int k = 0; k < JTC; ++k) {
            int j = jbase + k;
            float s = (j <= jmax) ? ss[q][k] * 0.125f : NEGV;
            ss[q][k] = s;
            acc += __expf(s);              // exp(-1e32) = 0 for masked
        }
        run[q] = acc;
    }
    // 4 interleaved inclusive scans across lanes (j-ordered)
    float sl[4] = { run[0], run[1], run[2], run[3] };
#pragma unroll
    for (int off = 1; off < 64; off <<= 1) {
        float n0 = __shfl_up(sl[0], off);
        float n1 = __shfl_up(sl[1], off);
        float n2 = __shfl_up(sl[2], off);
        float n3 = __shfl_up(sl[3], off);
        if (lane >= off) { sl[0] += n0; sl[1] += n1; sl[2] += n2; sl[3] += n3; }
    }

    // ---- loop B: LDS-free decay + second softmax (unnormalized) ---------
    float Z2[4];
#pragma unroll
    for (int q = 0; q < 4; ++q) {
        float excl = sl[q] - run[q];
        float Z = __shfl(sl[q], 63);
        float inv = 1.f / Z;
        int i = im + q;
        float csum = 0.f, z2 = 0.f;
#pragma unroll
        for (int k = 0; k < JTC; ++k) {
            int j = jbase + k;
            float s = ss[q][k];
            csum += __expf(s);                       // inclusive cumsum
            float rem = (Z - excl - csum) * inv;     // disttot - distcum
            float pos = fabsf((float)(i - j));
            float dd = fmaxf(rem * pos, 0.f);        // fmax(NaN,0)=0 safe
            float te = __expf(sqrtf(dd) * g);
            te = fminf(fmaxf(te, 1e-5f), 1e5f);
            float pe2 = __expf(s * te);              // masked: -1e32*te -> 0
            ss[q][k] = pe2;
            z2 += pe2;
        }
        Z2[q] = z2;
    }
    // 4 interleaved sum reductions
#pragma unroll
    for (int off = 32; off >= 1; off >>= 1) {
        Z2[0] += __shfl_xor(Z2[0], off);
        Z2[1] += __shfl_xor(Z2[1], off);
        Z2[2] += __shfl_xor(Z2[2], off);
        Z2[3] += __shfl_xor(Z2[3], off);
    }
    __syncthreads();   // ALL waves' Sc reads done; Ph may now overwrite Sc

    // ---- write normalized P f16 into swizzled Ph ------------------------
#pragma unroll
    for (int q = 0; q < 4; ++q) {
        int r = w * 4 + q;
        float inv2 = 1.f / Z2[q];
        int zp = (maskflag == 0) && (im + q == 0);
        if constexpr (JTC == 8) {
            int slot = (lane & ~7) | ((lane & 7) ^ (r & 7));
            f16x8 o8;
#pragma unroll
            for (int k = 0; k < 8; ++k)
                o8[k] = (f16)(zp ? 0.f : ss[q][k] * inv2);
            *(f16x8*)(Ph + r * 512 + slot * 8) = o8;
        } else if constexpr (JTC == 4) {
            int cj = lane >> 1;
            int slot = (cj & ~7) | ((cj & 7) ^ (r & 7));
            f16x4 o4;
#pragma unroll
            for (int k = 0; k < 4; ++k)
                o4[k] = (f16)(zp ? 0.f : ss[q][k] * inv2);
            *(f16x4*)(Ph + r * 512 + slot * 8 + (lane & 1) * 4) = o4;
        } else {
#pragma unroll
            for (int k = 0; k < JTC; ++k) {
                int j = jbase + k;
                int cj = j >> 3;
                int slot = (cj & ~7) | ((cj & 7) ^ (r & 7));
                Ph[r * 512 + slot * 8 + (j & 7)] =
                    (f16)(zp ? 0.f : ss[q][k] * inv2);
            }
        }
    }
    __syncthreads();

    // ---- Phase 3: O = P @ V, dual accumulator ---------------------------
    f32x4 oa0 = {}, oa1 = {};
#pragma unroll
    for (int f = 0; f < 2 * JTC; ++f) {
        f16x8 bv = *(const f16x8*)(vbase + (f >> 1) * 64 + (f & 1) * 32);
        int c = (f >> 1) * 8 + (f & 1) * 4 + rg;
        int slot = (c & ~7) | ((c & 7) ^ (ln & 7));
        f16x8 ap = *(const f16x8*)(Ph + ln * 512 + slot * 8);
        if (f & 1) oa1 = __builtin_amdgcn_mfma_f32_16x16x32_f16(ap, bv, oa1, 0, 0, 0);
        else       oa0 = __builtin_amdgcn_mfma_f32_16x16x32_f16(ap, bv, oa0, 0, 0, 0);
    }
    f32x4 oa = oa0 + oa1;
#pragma unroll
    for (int r = 0; r < 4; ++r)
        ob[(size_t)r * Dm] = (f16)oa[r];
}

// ---------------------------------------------------------------------------
// AKT attention. One block per (b, h, 16-row i-tile), 4 waves.
// XCD-chunked swizzle (proven: FETCH 61.5->8.3MB). Heavy-first LPT order.
// ---------------------------------------------------------------------------
__global__ __launch_bounds__(256, 4) void k_attn(
    const f16* __restrict__ Qh, const f16* __restrict__ VT,
    f16* __restrict__ O, const float* __restrict__ gam, int maskflag)
{
    __shared__ float Sc[16][516];
    f16* Ph = (f16*)Sc;          // 16KB alias, safe after post-read barrier

    int tid = threadIdx.x;
    int w = tid >> 6, lane = tid & 63;
    int ln = lane & 15, rg = lane >> 4;

    // XCD-chunked bijective remap (4096 blocks, 8 XCDs, 512 each)
    int bid = blockIdx.x;
    int lbid = (bid & 7) * 512 + (bid >> 3);
    int tile = 31 - (lbid & 31);        // heavy-first within each bh
    int bh = lbid >> 5;
    int b = bh >> 3, h = bh & 7;
    int i0 = tile * 16;
    int jtc = (tile >> 2) + 1;          // valid j-tiles (64 cols each)

    const f16* Qbase = Qh + ((size_t)b * Sl) * Dm + h * DKh;
    const f16* vbase = VT + ((size_t)bh * 64 + w * 16 + ln) * 512 + rg * 8;
    f16* ob = O + ((size_t)b * Sl + i0 + rg * 4) * Dm + h * DKh + w * 16 + ln;

    float gm = gam[h];
    float g = -((gm > 20.f) ? gm : log1pf(__expf(gm)));   // -softplus(gamma)

    // A-frags: Q rows i0..i0+15, reused across units
    f16x8 aq0 = *(const f16x8*)(Qbase + (size_t)(i0 + ln) * Dm + rg * 8);
    f16x8 aq1 = *(const f16x8*)(Qbase + (size_t)(i0 + ln) * Dm + 32 + rg * 8);

    switch (jtc) {
    case 1: attn_body<1>(Sc, Ph, Qbase, vbase, ob, aq0, aq1, g, w, lane, ln, rg, i0, maskflag); break;
    case 2: attn_body<2>(Sc, Ph, Qbase, vbase, ob, aq0, aq1, g, w, lane, ln, rg, i0, maskflag); break;
    case 3: attn_body<3>(Sc, Ph, Qbase, vbase, ob, aq0, aq1, g, w, lane, ln, rg, i0, maskflag); break;
    case 4: attn_body<4>(Sc, Ph, Qbase, vbase, ob, aq0, aq1, g, w, lane, ln, rg, i0, maskflag); break;
    case 5: attn_body<5>(Sc, Ph, Qbase, vbase, ob, aq0, aq1, g, w, lane, ln, rg, i0, maskflag); break;
    case 6: attn_body<6>(Sc, Ph, Qbase, vbase, ob, aq0, aq1, g, w, lane, ln, rg, i0, maskflag); break;
    case 7: attn_body<7>(Sc, Ph, Qbase, vbase, ob, aq0, aq1, g, w, lane, ln, rg, i0, maskflag); break;
    default: attn_body<8>(Sc, Ph, Qbase, vbase, ob, aq0, aq1, g, w, lane, ln, rg, i0, maskflag); break;
    }
}

// ---------------------------------------------------------------------------
// Residual + LayerNorm: Out = LN(Xn + Rr)*g + b, dual f32+f16 output.
// ---------------------------------------------------------------------------
__global__ __launch_bounds__(256) void k_ln(
    const float* __restrict__ Xn, const float* __restrict__ Rr,
    const float* __restrict__ gw, const float* __restrict__ bw,
    float* __restrict__ Out, f16* __restrict__ Outh)
{
    int tid = threadIdx.x;
    int w = tid >> 6, lane = tid & 63;
    int row = blockIdx.x * 4 + w;
    const float* xr = Xn + (size_t)row * Dm;
    const float* rr = Rr + (size_t)row * Dm;
    int c0 = lane * 4, c1 = 256 + lane * 4;
    float4 va = *(const float4*)(xr + c0);
    float4 vb = *(const float4*)(xr + c1);
    float4 ra = *(const float4*)(rr + c0);
    float4 rb = *(const float4*)(rr + c1);
    va.x += ra.x; va.y += ra.y; va.z += ra.z; va.w += ra.w;
    vb.x += rb.x; vb.y += rb.y; vb.z += rb.z; vb.w += rb.w;
    float sum = va.x + va.y + va.z + va.w + vb.x + vb.y + vb.z + vb.w;
#pragma unroll
    for (int off = 32; off >= 1; off >>= 1) sum += __shfl_xor(sum, off);
    float mu = sum * (1.f / 512.f);
    float var = 0.f;
    {
        float d;
        d = va.x - mu; var += d * d;  d = va.y - mu; var += d * d;
        d = va.z - mu; var += d * d;  d = va.w - mu; var += d * d;
        d = vb.x - mu; var += d * d;  d = vb.y - mu; var += d * d;
        d = vb.z - mu; var += d * d;  d = vb.w - mu; var += d * d;
    }
#pragma unroll
    for (int off = 32; off >= 1; off >>= 1) var += __shfl_xor(var, off);
    float rs = rsqrtf(var * (1.f / 512.f) + 1e-5f);
    float4 ga = *(const float4*)(gw + c0);
    float4 gb = *(const float4*)(gw + c1);
    float4 ba = *(const float4*)(bw + c0);
    float4 bb = *(const float4*)(bw + c1);
    float4 oa, ob;
    oa.x = (va.x - mu) * rs * ga.x + ba.x;  oa.y = (va.y - mu) * rs * ga.y + ba.y;
    oa.z = (va.z - mu) * rs * ga.z + ba.z;  oa.w = (va.w - mu) * rs * ga.w + ba.w;
    ob.x = (vb.x - mu) * rs * gb.x + bb.x;  ob.y = (vb.y - mu) * rs * gb.y + bb.y;
    ob.z = (vb.z - mu) * rs * gb.z + bb.z;  ob.w = (vb.w - mu) * rs * gb.w + bb.w;
    float* orow = Out + (size_t)row * Dm;
    f16* ohrow = Outh + (size_t)row * Dm;
    *(float4*)(orow + c0) = oa;
    *(float4*)(orow + c1) = ob;
    f16x4 ha = { (f16)oa.x, (f16)oa.y, (f16)oa.z, (f16)oa.w };
    f16x4 hb = { (f16)ob.x, (f16)ob.y, (f16)ob.z, (f16)ob.w };
    *(f16x4*)(ohrow + c0) = ha;
    *(f16x4*)(ohrow + c1) = hb;
}

// ---------------------------------------------------------------------------
extern "C" void kernel_launch(void* const* d_in, const int* in_sizes, int n_in,
                              void* d_out, int out_size, void* d_ws, size_t ws_size,
                              hipStream_t stream)
{
    const float* q_emb  = (const float*)d_in[0];
    const float* qa_emb = (const float*)d_in[1];
    const float* Wk  = (const float*)d_in[3];
    const float* bk  = (const float*)d_in[4];
    const float* Wv  = (const float*)d_in[5];
    const float* bv  = (const float*)d_in[6];
    const float* Wo  = (const float*)d_in[7];
    const float* bo  = (const float*)d_in[8];
    const float* gam = (const float*)d_in[9];
    const float* l1g = (const float*)d_in[10];
    const float* l1b = (const float*)d_in[11];
    const float* W1  = (const float*)d_in[12];
    const float* b1  = (const float*)d_in[13];
    const float* W2  = (const float*)d_in[14];
    const float* b2  = (const float*)d_in[15];
    const float* l2g = (const float*)d_in[16];
    const float* l2b = (const float*)d_in[17];
    float* outp = (float*)d_out;

    const size_t NE  = (size_t)MROWS * Dm;    // 4194304
    const size_t WDD = (size_t)Dm * Dm;
    const size_t WDF = (size_t)Dm * DFFn;
    const size_t WKV = 2 * WDD;               // concat KV slice [1024][512]

    float* xbuf = (float*)d_ws;               // NE f32
    float* ybuf = xbuf + NE;                  // NE f32
    float* t2   = ybuf + NE;                  // NE f32 (LN input temp)
    f16* xh  = (f16*)(t2 + NE);               // NE
    f16* yh  = xh + NE;                       // NE
    f16* R   = yh + NE;                       // 4*NE f16 region
    f16* qh  = R;                             // q(=k) heads f16
    f16* vt  = R + 2 * NE;                    // v transposed per head (fused)
    f16* t1h = R + 3 * NE;                    // attention output f16
    f16* fbh = R;                             // FFN hidden (aliases R, 4*NE)
    f16* wkvh = R + 4 * NE;                   // concat KV weights [6][1024][512]
    f16* woh = wkvh + 6 * WKV;
    f16* w1h = woh + 6 * WDD;                 // slots 0,1,3,5
    f16* w2h = w1h + 4 * WDF;
    float* bkv = (float*)(w2h + 4 * WDF);     // [6][1024] f32

    // ---- single prep launch: weight convert + bias concat + input copies
    PrepArgs pa;
    pa.Wk = Wk; pa.Wv = Wv; pa.Wo = Wo; pa.W1 = W1; pa.W2 = W2;
    pa.bk = bk; pa.bv = bv; pa.q_emb = q_emb; pa.qa_emb = qa_emb;
    pa.wkvh = wkvh; pa.woh = woh; pa.w1h = w1h; pa.w2h = w2h;
    pa.bkv = bkv; pa.xbuf = xbuf; pa.ybuf = ybuf; pa.xh = xh; pa.yh = yh;
    k_prep<<<45592, 256, 0, stream>>>(pa);

    // finalOut: if non-null, the LAST LayerNorm's f32 result goes there
    // (the f32 residual stream is dead afterwards; f16 mirror still written).
    auto layer = [&](int l, int maskflag, float* Xq, f16* Xqh, f16* Xvh,
                     bool apply_pos, float* finalOut) {
        if (Xqh == Xvh) {
            // fused KV projection: N=1024, 512 blocks (2/CU)
            k_gemm<0, 1, 2, 1><<<dim3(1024 / 128, MROWS / 128), 256, 0, stream>>>(
                Xqh, wkvh + (size_t)l * WKV, bkv + l * 1024, (float*)vt, qh,
                MROWS, 1024, Dm, nullptr, nullptr);
        } else {
            // DUAL: K-proj of Xqh and V-proj of Xvh in one 512-block launch
            k_gemm<0, 1, 3, 1><<<dim3(8, MROWS / 128), 256, 0, stream>>>(
                Xqh, wkvh + (size_t)l * WKV, bkv + l * 1024, nullptr, qh,
                MROWS, 512, Dm, Xvh, vt);
        }
        k_attn<<<Bsz * Hn * 32, 256, 0, stream>>>(qh, vt, t1h, gam + l * Hn, maskflag);
        k_gemm<0, 0, 0, 1><<<dim3(Dm / 128, MROWS / 128), 256, 0, stream>>>(
            t1h, woh + (size_t)l * WDD, bo + l * Dm, t2, nullptr,
            MROWS, Dm, Dm, nullptr, nullptr);
        if (apply_pos) {
            k_ln<<<MROWS / 4, 256, 0, stream>>>(t2, Xq, l1g + l * Dm, l1b + l * Dm, Xq, Xqh);
            int sl = (l < 2) ? l : ((l + 1) >> 1);
            k_gemm<1, 1, 0, 0><<<dim3(DFFn / 128, MROWS / 128), 256, 0, stream>>>(
                Xqh, w1h + (size_t)sl * WDF, b1 + l * DFFn, nullptr, fbh,
                MROWS, DFFn, Dm, nullptr, nullptr);
            k_gemm<0, 0, 0, 1><<<dim3(Dm / 128, MROWS / 128), 256, 0, stream>>>(
                fbh, w2h + (size_t)sl * WDF, b2 + l * Dm, t2, nullptr,
                MROWS, Dm, DFFn, nullptr, nullptr);
            k_ln<<<MROWS / 4, 256, 0, stream>>>(t2, Xq, l2g + l * Dm, l2b + l * Dm,
                                                finalOut ? finalOut : Xq, Xqh);
        } else {
            k_ln<<<MROWS / 4, 256, 0, stream>>>(t2, Xq, l1g + l * Dm, l1b + l * Dm,
                                                finalOut ? finalOut : Xq, Xqh);
        }
    };

    const size_t NEo = NE;
    // blocks_1: self-attn on y, mask=1, FFN. Layer 1 is y's final write -> out+NE.
    layer(0, 1, ybuf, yh, yh, true, nullptr);
    layer(1, 1, ybuf, yh, yh, true, outp + NEo);
    // blocks_2: (mask=1, no FFN) then (mask=0, values=y, FFN), twice.
    // Layer 5 is x's final write -> out.
    layer(2, 1, xbuf, xh, xh, false, nullptr);
    layer(3, 0, xbuf, xh, yh, true, nullptr);
    layer(4, 1, xbuf, xh, xh, false, nullptr);
    layer(5, 0, xbuf, xh, yh, true, outp);
}

// Round 9
// 1153.337 us; speedup vs baseline: 1.0727x; 1.0727x over previous
//
#include <hip/hip_runtime.h>
#include <hip/hip_bf16.h>

// Problem constants (AKT core): B=16, S=512, D=512, H=8, DFF=2048, NB=2, L=6
#define Bsz  16
#define Sl   512
#define Dm   512
#define Hn   8
#define DKh  64
#define DFFn 2048
#define MROWS (Bsz * Sl)      // 8192
#define NEGV (-1e32f)

typedef _Float16 f16;
typedef f16 f16x8 __attribute__((ext_vector_type(8)));
typedef f16 f16x4 __attribute__((ext_vector_type(4)));
typedef float f32x4 __attribute__((ext_vector_type(4)));

// async global->LDS, 16B per lane: lds dst = wave-uniform base + lane*16
#define GLDS16(g, l) __builtin_amdgcn_global_load_lds( \
    (const __attribute__((address_space(1))) void*)(g), \
    (__attribute__((address_space(3))) void*)(l), 16, 0, 0)

// ---------------------------------------------------------------------------
// k_prep: all one-off preprocessing in ONE launch (fewer dispatch gaps).
// ---------------------------------------------------------------------------
struct PrepArgs {
    const float *Wk, *Wv, *Wo, *W1, *W2, *bk, *bv, *q_emb, *qa_emb;
    f16 *wkvh, *woh, *w1h, *w2h;
    float *bkv, *xbuf, *ybuf;
    f16 *xh, *yh;
};

__device__ __forceinline__ void wconv_body(const float* src, f16* dst,
        int K, int N, int lmap, size_t zstride, int z, int nx, int ny,
        int t, float (*T)[36])
{
    int ls = lmap ? (z < 2 ? z : 2 * z - 1) : z;
    const float* S = src + (size_t)ls * K * N;
    f16* Dt = dst + (size_t)z * zstride;
    int n0 = nx * 32, k0 = ny * 32;
    int r = t >> 3, c = (t & 7) * 4;
    float4 v = *(const float4*)(S + (size_t)(k0 + r) * N + n0 + c);
    T[r][c] = v.x; T[r][c + 1] = v.y; T[r][c + 2] = v.z; T[r][c + 3] = v.w;
    __syncthreads();
    int n = t >> 3, kq = (t & 7) * 4;
    f16x4 o = { (f16)T[kq][n], (f16)T[kq + 1][n], (f16)T[kq + 2][n], (f16)T[kq + 3][n] };
    *(f16x4*)(Dt + (size_t)(n0 + n) * K + k0 + kq) = o;
}

__global__ __launch_bounds__(256) void k_prep(PrepArgs a)
{
    __shared__ float T[32][36];
    int id = blockIdx.x;
    int t = threadIdx.x;
    const size_t WDD = (size_t)Dm * Dm;
    const size_t WDF = (size_t)Dm * DFFn;
    const size_t WKV = 2 * WDD;

    if (id < 4608) {
        int which = id / 1536, rest = id % 1536;
        int z = rest >> 8, r2 = rest & 255;
        int nx = r2 & 15, ny = r2 >> 4;
        if (which == 0)      wconv_body(a.Wk, a.wkvh,       Dm, Dm, 0, WKV, z, nx, ny, t, T);
        else if (which == 1) wconv_body(a.Wv, a.wkvh + WDD, Dm, Dm, 0, WKV, z, nx, ny, t, T);
        else                 wconv_body(a.Wo, a.woh,        Dm, Dm, 0, WDD, z, nx, ny, t, T);
    } else if (id < 8704) {
        int id2 = id - 4608;
        int z = id2 >> 10, r2 = id2 & 1023;
        int nx = r2 & 63, ny = r2 >> 6;          // N=2048: 64 x-tiles, 16 y
        wconv_body(a.W1, a.w1h, Dm, DFFn, 1, WDF, z, nx, ny, t, T);
    } else if (id < 12800) {
        int id3 = id - 8704;
        int z = id3 >> 10, r2 = id3 & 1023;
        int nx = r2 & 15, ny = r2 >> 4;          // K=2048: 16 x, 64 y
        wconv_body(a.W2, a.w2h, DFFn, Dm, 1, WDF, z, nx, ny, t, T);
    } else if (id < 12824) {
        int i = (id - 12800) * 256 + t;          // 6*1024
        int z = i >> 10, c = i & 1023;
        a.bkv[i] = (c < 512) ? a.bk[z * 512 + c] : a.bv[z * 512 + c - 512];
    } else if (id < 29208) {
        int i = (id - 12824) * 256 + t;
        float v = a.q_emb[i];
        a.xbuf[i] = v; a.xh[i] = (f16)v;
    } else {
        int i = (id - 29208) * 256 + t;
        float v = a.qa_emb[i];
        a.ybuf[i] = v; a.yh[i] = (f16)v;
    }
}

// ---------------------------------------------------------------------------
// MFMA f16 GEMM: C[M,N] = A[M,K] @ Bt[N,K]^T + bias[N]. A,Bt f16; bias f32.
// BM x 128 tile (BM=128 or 64), 4 waves (2x2, each BM/2 x 64), 16x16x32 MFMA.
// 2-buffer __syncthreads pipeline (PROVEN round-7 state; the 3-buffer
// counted-vmcnt variant regressed: 96KB LDS halved blocks/CU — lesson 15).
// BM=64 (48KB LDS): for grid-limited N=512 GEMMs -> 512 blocks = 2/CU.
// VTOUT=1: vt[bh][d][s] layout. VTOUT=2: fused KV N=1024. VTOUT=3: dual
//   independent projections (bx<4 -> qh, bx>=4 -> A2@Bt[512:] -> vt).
// ---------------------------------------------------------------------------
template <int RELU, int OUT16, int VTOUT, int BK64, int BM>
__global__ __launch_bounds__(256) void k_gemm(
    const f16* __restrict__ A, const f16* __restrict__ Bt,
    const float* __restrict__ bias, float* __restrict__ C, f16* __restrict__ Ch,
    int M, int N, int K,
    const f16* __restrict__ A2, f16* __restrict__ Ch2)
{
    constexpr int HL = BK64 ? 2 : 1;        // 32-wide halves per K-step
    constexpr int MI = BM / 32;             // i-frags per wave (4 or 2)
    constexpr int MW = BM / 2;              // wave M-extent
    constexpr int AHALF = BM * 32;          // f16 per A half-tile
    constexpr int ABUF = HL * AHALF;
    constexpr int BBUF = HL * 4096;
    __shared__ f16 As[2 * ABUF];
    __shared__ f16 Bs[2 * BBUF];
    int tid = threadIdx.x;
    int w = tid >> 6, lane = tid & 63;
    int ln = lane & 15, rg = lane >> 4;
    int wr = w >> 1, wc = w & 1;
    int m0 = blockIdx.y * BM;
    int half = (VTOUT == 3) ? (blockIdx.x >> 2) : 0;
    int n0 = (VTOUT == 3) ? (blockIdx.x & 3) * 128 : blockIdx.x * 128;

    const f16* Ause = (VTOUT == 3 && half) ? A2 : A;
    const f16* Btuse = (VTOUT == 3) ? Bt + (size_t)half * 512 * 512 : Bt;
    const float* biasuse = (VTOUT == 3) ? bias + half * 512 : bias;

    int s0 = tid, s1 = 256 + tid;
    int r0s = s0 >> 2, c0s = ((s0 & 3) ^ ((s0 >> 3) & 3));
    int r1s = s1 >> 2, c1s = ((s1 & 3) ^ ((s1 >> 3) & 3));

    const f16* a0 = Ause + (size_t)(m0 + r0s) * K + c0s * 8;
    const f16* a1 = Ause + (size_t)(m0 + (BM == 128 ? r1s : r0s)) * K
                    + (BM == 128 ? c1s : c0s) * 8;   // unused rows clamp for BM64
    const f16* b0 = Btuse + (size_t)(n0 + r0s) * K + c0s * 8;
    const f16* b1 = Btuse + (size_t)(n0 + r1s) * K + c1s * 8;

    int cc8 = (rg ^ ((ln >> 1) & 3)) * 8;

    f32x4 acc[MI][4] = {};

    int nk = K >> (BK64 ? 6 : 5);

    auto STAGE = [&](int nb, int kt) {
        f16* lA = As + nb * ABUF + w * 512;
        f16* lB = Bs + nb * BBUF + w * 512;
#pragma unroll
        for (int hh = 0; hh < HL; ++hh) {
            GLDS16(a0 + kt + hh * 32, lA + hh * AHALF);
            if (BM == 128) GLDS16(a1 + kt + hh * 32, lA + hh * AHALF + 2048);
            GLDS16(b0 + kt + hh * 32, lB + hh * 4096);
            GLDS16(b1 + kt + hh * 32, lB + hh * 4096 + 2048);
        }
    };

    auto COMPUTE = [&](int nb) {
#pragma unroll
        for (int hh = 0; hh < HL; ++hh) {
            const f16* Ab = As + nb * ABUF + hh * AHALF;
            const f16* Bb = Bs + nb * BBUF + hh * 4096;
            f16x8 af[MI], bf[4];
#pragma unroll
            for (int i = 0; i < MI; ++i) {
                int m = wr * MW + i * 16 + ln;
                af[i] = *(const f16x8*)(Ab + m * 32 + cc8);
            }
#pragma unroll
            for (int j = 0; j < 4; ++j) {
                int nn = wc * 64 + j * 16 + ln;
                bf[j] = *(const f16x8*)(Bb + nn * 32 + cc8);
            }
#pragma unroll
            for (int i = 0; i < MI; ++i)
#pragma unroll
                for (int j = 0; j < 4; ++j)
                    acc[i][j] = __builtin_amdgcn_mfma_f32_16x16x32_f16(af[i], bf[j], acc[i][j], 0, 0, 0);
        }
    };

    STAGE(0, 0);
    __syncthreads();   // vmcnt(0) drain: buf0 ready
    int cur = 0;
    for (int t = 0; t < nk; ++t) {
        if (t + 1 < nk) STAGE(cur ^ 1, (t + 1) << (BK64 ? 6 : 5));
        COMPUTE(cur);
        __syncthreads();   // drains vmcnt(0): next buffer staged, reads done
        cur ^= 1;
    }

#pragma unroll
    for (int j = 0; j < 4; ++j) {
        int col = n0 + wc * 64 + j * 16 + ln;
        float bj = biasuse[col];
#pragma unroll
        for (int i = 0; i < MI; ++i) {
            int rb = m0 + wr * MW + i * 16 + rg * 4;
            if constexpr (VTOUT == 1) {
                // vt[((b*8+h)*64 + dk)*512 + s], s = 4 consecutive rows
                int bq = rb >> 9, s = rb & 511;
                int hh = col >> 6, dk = col & 63;
                f16x4 o;
#pragma unroll
                for (int r = 0; r < 4; ++r) o[r] = (f16)(acc[i][j][r] + bj);
                *(f16x4*)(Ch + (((size_t)(bq * 8 + hh) * 64 + dk) << 9) + s) = o;
            } else if constexpr (VTOUT == 2) {
                if (n0 < 512) {       // qh half (block-uniform branch)
#pragma unroll
                    for (int r = 0; r < 4; ++r)
                        Ch[(size_t)(rb + r) * 512 + col] = (f16)(acc[i][j][r] + bj);
                } else {              // vt half
                    f16* Cv = (f16*)C;
                    int colv = col - 512;
                    int bq = rb >> 9, s = rb & 511;
                    int hh = colv >> 6, dk = colv & 63;
                    f16x4 o;
#pragma unroll
                    for (int r = 0; r < 4; ++r) o[r] = (f16)(acc[i][j][r] + bj);
                    *(f16x4*)(Cv + (((size_t)(bq * 8 + hh) * 64 + dk) << 9) + s) = o;
                }
            } else if constexpr (VTOUT == 3) {
                if (half == 0) {      // qh
#pragma unroll
                    for (int r = 0; r < 4; ++r)
                        Ch[(size_t)(rb + r) * 512 + col] = (f16)(acc[i][j][r] + bj);
                } else {              // vt
                    int bq = rb >> 9, s = rb & 511;
                    int hh = col >> 6, dk = col & 63;
                    f16x4 o;
#pragma unroll
                    for (int r = 0; r < 4; ++r) o[r] = (f16)(acc[i][j][r] + bj);
                    *(f16x4*)(Ch2 + (((size_t)(bq * 8 + hh) * 64 + dk) << 9) + s) = o;
                }
            } else {
#pragma unroll
                for (int r = 0; r < 4; ++r) {
                    float v = acc[i][j][r] + bj;
                    if (RELU) v = fmaxf(v, 0.f);
                    if (OUT16) Ch[(size_t)(rb + r) * N + col] = (f16)v;
                    else       C [(size_t)(rb + r) * N + col] = v;
                }
            }
        }
    }
}

// ---------------------------------------------------------------------------
// AKT attention body, specialized on JTC. Scores in registers after one
// vectorized LDS read; loop B LDS-free.
// ---------------------------------------------------------------------------
template <int JTC>
__device__ __forceinline__ void attn_body(
    float (*Sc)[516], f16* Ph, const f16* Qbase, const f16* vbase, f16* ob,
    f16x8 aq0, f16x8 aq1, float g,
    int w, int lane, int ln, int rg, int i0, int maskflag)
{
    // ---- Phase 1: scores, 16-col unit granularity across waves ----------
#pragma unroll
    for (int ui = 0; ui < JTC; ++ui) {
        int u = w + ui * 4;
        const f16* kb = Qbase + (size_t)(u * 16 + ln) * Dm + rg * 8;
        f16x8 b0 = *(const f16x8*)(kb);
        f16x8 b1 = *(const f16x8*)(kb + 32);
        f32x4 c = {};
        c = __builtin_amdgcn_mfma_f32_16x16x32_f16(aq0, b0, c, 0, 0, 0);
        c = __builtin_amdgcn_mfma_f32_16x16x32_f16(aq1, b1, c, 0, 0, 0);
#pragma unroll
        for (int r = 0; r < 4; ++r)
            Sc[rg * 4 + r][u * 16 + ln] = c[r];
    }
    __syncthreads();

    int jbase = lane * JTC;
    int im = i0 + w * 4;

    // ---- loop A: vector-read scores -> regs, mask+scale, first exp-sums -
    float ss[4][JTC];
    float run[4];
#pragma unroll
    for (int q = 0; q < 4; ++q) {
        const float* Srow = &Sc[w * 4 + q][0];
        if constexpr (JTC == 8) {
            float4 t0 = *(const float4*)(Srow + jbase);
            float4 t1 = *(const float4*)(Srow + jbase + 4);
            ss[q][0] = t0.x; ss[q][1] = t0.y; ss[q][2] = t0.z; ss[q][3] = t0.w;
            ss[q][4] = t1.x; ss[q][5] = t1.y; ss[q][6] = t1.z; ss[q][7] = t1.w;
        } else if constexpr (JTC == 4) {
            float4 t0 = *(const float4*)(Srow + jbase);
            ss[q][0] = t0.x; ss[q][1] = t0.y; ss[q][2] = t0.z; ss[q][3] = t0.w;
        } else {
#pragma unroll
            for (int k = 0; k < JTC; ++k) ss[q][k] = Srow[jbase + k];
        }
        int jmax = maskflag ? (im + q) : (im + q - 1);
        float acc = 0.f;
#pragma unroll
        for (int k = 0; k < JTC; ++k) {
            int j = jbase + k;
            float s = (j <= jmax) ? ss[q][k] * 0.125f : NEGV;
            ss[q][k] = s;
            acc += __expf(s);              // exp(-1e32) = 0 for masked
        }
        run[q] = acc;
    }
    // 4 interleaved inclusive scans across lanes (j-ordered)
    float sl[4] = { run[0], run[1], run[2], run[3] };
#pragma unroll
    for (int off = 1; off < 64; off <<= 1) {
        float n0 = __shfl_up(sl[0], off);
        float n1 = __shfl_up(sl[1], off);
        float n2 = __shfl_up(sl[2], off);
        float n3 = __shfl_up(sl[3], off);
        if (lane >= off) { sl[0] += n0; sl[1] += n1; sl[2] += n2; sl[3] += n3; }
    }

    // ---- loop B: LDS-free decay + second softmax (unnormalized) ---------
    float Z2[4];
#pragma unroll
    for (int q = 0; q < 4; ++q) {
        float excl = sl[q] - run[q];
        float Z = __shfl(sl[q], 63);
        float inv = 1.f / Z;
        int i = im + q;
        float csum = 0.f, z2 = 0.f;
#pragma unroll
        for (int k = 0; k < JTC; ++k) {
            int j = jbase + k;
            float s = ss[q][k];
            csum += __expf(s);                       // inclusive cumsum
            float rem = (Z - excl - csum) * inv;     // disttot - distcum
            float pos = fabsf((float)(i - j));
            float dd = fmaxf(rem * pos, 0.f);        // fmax(NaN,0)=0 safe
            float te = __expf(sqrtf(dd) * g);
            te = fminf(fmaxf(te, 1e-5f), 1e5f);
            float pe2 = __expf(s * te);              // masked: -1e32*te -> 0
            ss[q][k] = pe2;
            z2 += pe2;
        }
        Z2[q] = z2;
    }
    // 4 interleaved sum reductions
#pragma unroll
    for (int off = 32; off >= 1; off >>= 1) {
        Z2[0] += __shfl_xor(Z2[0], off);
        Z2[1] += __shfl_xor(Z2[1], off);
        Z2[2] += __shfl_xor(Z2[2], off);
        Z2[3] += __shfl_xor(Z2[3], off);
    }
    __syncthreads();   // ALL waves' Sc reads done; Ph may now overwrite Sc

    // ---- write normalized P f16 into swizzled Ph ------------------------
#pragma unroll
    for (int q = 0; q < 4; ++q) {
        int r = w * 4 + q;
        float inv2 = 1.f / Z2[q];
        int zp = (maskflag == 0) && (im + q == 0);
        if constexpr (JTC == 8) {
            int slot = (lane & ~7) | ((lane & 7) ^ (r & 7));
            f16x8 o8;
#pragma unroll
            for (int k = 0; k < 8; ++k)
                o8[k] = (f16)(zp ? 0.f : ss[q][k] * inv2);
            *(f16x8*)(Ph + r * 512 + slot * 8) = o8;
        } else if constexpr (JTC == 4) {
            int cj = lane >> 1;
            int slot = (cj & ~7) | ((cj & 7) ^ (r & 7));
            f16x4 o4;
#pragma unroll
            for (int k = 0; k < 4; ++k)
                o4[k] = (f16)(zp ? 0.f : ss[q][k] * inv2);
            *(f16x4*)(Ph + r * 512 + slot * 8 + (lane & 1) * 4) = o4;
        } else {
#pragma unroll
            for (int k = 0; k < JTC; ++k) {
                int j = jbase + k;
                int cj = j >> 3;
                int slot = (cj & ~7) | ((cj & 7) ^ (r & 7));
                Ph[r * 512 + slot * 8 + (j & 7)] =
                    (f16)(zp ? 0.f : ss[q][k] * inv2);
            }
        }
    }
    __syncthreads();

    // ---- Phase 3: O = P @ V, dual accumulator ---------------------------
    f32x4 oa0 = {}, oa1 = {};
#pragma unroll
    for (int f = 0; f < 2 * JTC; ++f) {
        f16x8 bv = *(const f16x8*)(vbase + (f >> 1) * 64 + (f & 1) * 32);
        int c = (f >> 1) * 8 + (f & 1) * 4 + rg;
        int slot = (c & ~7) | ((c & 7) ^ (ln & 7));
        f16x8 ap = *(const f16x8*)(Ph + ln * 512 + slot * 8);
        if (f & 1) oa1 = __builtin_amdgcn_mfma_f32_16x16x32_f16(ap, bv, oa1, 0, 0, 0);
        else       oa0 = __builtin_amdgcn_mfma_f32_16x16x32_f16(ap, bv, oa0, 0, 0, 0);
    }
    f32x4 oa = oa0 + oa1;
#pragma unroll
    for (int r = 0; r < 4; ++r)
        ob[(size_t)r * Dm] = (f16)oa[r];
}

// ---------------------------------------------------------------------------
// AKT attention. One block per (b, h, 16-row i-tile), 4 waves.
// XCD-chunked swizzle (proven: FETCH 61.5->8.3MB). Heavy-first LPT order.
// ---------------------------------------------------------------------------
__global__ __launch_bounds__(256, 4) void k_attn(
    const f16* __restrict__ Qh, const f16* __restrict__ VT,
    f16* __restrict__ O, const float* __restrict__ gam, int maskflag)
{
    __shared__ float Sc[16][516];
    f16* Ph = (f16*)Sc;          // 16KB alias, safe after post-read barrier

    int tid = threadIdx.x;
    int w = tid >> 6, lane = tid & 63;
    int ln = lane & 15, rg = lane >> 4;

    // XCD-chunked bijective remap (4096 blocks, 8 XCDs, 512 each)
    int bid = blockIdx.x;
    int lbid = (bid & 7) * 512 + (bid >> 3);
    int tile = 31 - (lbid & 31);        // heavy-first within each bh
    int bh = lbid >> 5;
    int b = bh >> 3, h = bh & 7;
    int i0 = tile * 16;
    int jtc = (tile >> 2) + 1;          // valid j-tiles (64 cols each)

    const f16* Qbase = Qh + ((size_t)b * Sl) * Dm + h * DKh;
    const f16* vbase = VT + ((size_t)bh * 64 + w * 16 + ln) * 512 + rg * 8;
    f16* ob = O + ((size_t)b * Sl + i0 + rg * 4) * Dm + h * DKh + w * 16 + ln;

    float gm = gam[h];
    float g = -((gm > 20.f) ? gm : log1pf(__expf(gm)));   // -softplus(gamma)

    // A-frags: Q rows i0..i0+15, reused across units
    f16x8 aq0 = *(const f16x8*)(Qbase + (size_t)(i0 + ln) * Dm + rg * 8);
    f16x8 aq1 = *(const f16x8*)(Qbase + (size_t)(i0 + ln) * Dm + 32 + rg * 8);

    switch (jtc) {
    case 1: attn_body<1>(Sc, Ph, Qbase, vbase, ob, aq0, aq1, g, w, lane, ln, rg, i0, maskflag); break;
    case 2: attn_body<2>(Sc, Ph, Qbase, vbase, ob, aq0, aq1, g, w, lane, ln, rg, i0, maskflag); break;
    case 3: attn_body<3>(Sc, Ph, Qbase, vbase, ob, aq0, aq1, g, w, lane, ln, rg, i0, maskflag); break;
    case 4: attn_body<4>(Sc, Ph, Qbase, vbase, ob, aq0, aq1, g, w, lane, ln, rg, i0, maskflag); break;
    case 5: attn_body<5>(Sc, Ph, Qbase, vbase, ob, aq0, aq1, g, w, lane, ln, rg, i0, maskflag); break;
    case 6: attn_body<6>(Sc, Ph, Qbase, vbase, ob, aq0, aq1, g, w, lane, ln, rg, i0, maskflag); break;
    case 7: attn_body<7>(Sc, Ph, Qbase, vbase, ob, aq0, aq1, g, w, lane, ln, rg, i0, maskflag); break;
    default: attn_body<8>(Sc, Ph, Qbase, vbase, ob, aq0, aq1, g, w, lane, ln, rg, i0, maskflag); break;
    }
}

// ---------------------------------------------------------------------------
// Residual + LayerNorm: Out = LN(Xn + Rr)*g + b, dual f32+f16 output.
// ---------------------------------------------------------------------------
__global__ __launch_bounds__(256) void k_ln(
    const float* __restrict__ Xn, const float* __restrict__ Rr,
    const float* __restrict__ gw, const float* __restrict__ bw,
    float* __restrict__ Out, f16* __restrict__ Outh)
{
    int tid = threadIdx.x;
    int w = tid >> 6, lane = tid & 63;
    int row = blockIdx.x * 4 + w;
    const float* xr = Xn + (size_t)row * Dm;
    const float* rr = Rr + (size_t)row * Dm;
    int c0 = lane * 4, c1 = 256 + lane * 4;
    float4 va = *(const float4*)(xr + c0);
    float4 vb = *(const float4*)(xr + c1);
    float4 ra = *(const float4*)(rr + c0);
    float4 rb = *(const float4*)(rr + c1);
    va.x += ra.x; va.y += ra.y; va.z += ra.z; va.w += ra.w;
    vb.x += rb.x; vb.y += rb.y; vb.z += rb.z; vb.w += rb.w;
    float sum = va.x + va.y + va.z + va.w + vb.x + vb.y + vb.z + vb.w;
#pragma unroll
    for (int off = 32; off >= 1; off >>= 1) sum += __shfl_xor(sum, off);
    float mu = sum * (1.f / 512.f);
    float var = 0.f;
    {
        float d;
        d = va.x - mu; var += d * d;  d = va.y - mu; var += d * d;
        d = va.z - mu; var += d * d;  d = va.w - mu; var += d * d;
        d = vb.x - mu; var += d * d;  d = vb.y - mu; var += d * d;
        d = vb.z - mu; var += d * d;  d = vb.w - mu; var += d * d;
    }
#pragma unroll
    for (int off = 32; off >= 1; off >>= 1) var += __shfl_xor(var, off);
    float rs = rsqrtf(var * (1.f / 512.f) + 1e-5f);
    float4 ga = *(const float4*)(gw + c0);
    float4 gb = *(const float4*)(gw + c1);
    float4 ba = *(const float4*)(bw + c0);
    float4 bb = *(const float4*)(bw + c1);
    float4 oa, ob;
    oa.x = (va.x - mu) * rs * ga.x + ba.x;  oa.y = (va.y - mu) * rs * ga.y + ba.y;
    oa.z = (va.z - mu) * rs * ga.z + ba.z;  oa.w = (va.w - mu) * rs * ga.w + ba.w;
    ob.x = (vb.x - mu) * rs * gb.x + bb.x;  ob.y = (vb.y - mu) * rs * gb.y + bb.y;
    ob.z = (vb.z - mu) * rs * gb.z + bb.z;  ob.w = (vb.w - mu) * rs * gb.w + bb.w;
    float* orow = Out + (size_t)row * Dm;
    f16* ohrow = Outh + (size_t)row * Dm;
    *(float4*)(orow + c0) = oa;
    *(float4*)(orow + c1) = ob;
    f16x4 ha = { (f16)oa.x, (f16)oa.y, (f16)oa.z, (f16)oa.w };
    f16x4 hb = { (f16)ob.x, (f16)ob.y, (f16)ob.z, (f16)ob.w };
    *(f16x4*)(ohrow + c0) = ha;
    *(f16x4*)(ohrow + c1) = hb;
}

// ---------------------------------------------------------------------------
extern "C" void kernel_launch(void* const* d_in, const int* in_sizes, int n_in,
                              void* d_out, int out_size, void* d_ws, size_t ws_size,
                              hipStream_t stream)
{
    const float* q_emb  = (const float*)d_in[0];
    const float* qa_emb = (const float*)d_in[1];
    const float* Wk  = (const float*)d_in[3];
    const float* bk  = (const float*)d_in[4];
    const float* Wv  = (const float*)d_in[5];
    const float* bv  = (const float*)d_in[6];
    const float* Wo  = (const float*)d_in[7];
    const float* bo  = (const float*)d_in[8];
    const float* gam = (const float*)d_in[9];
    const float* l1g = (const float*)d_in[10];
    const float* l1b = (const float*)d_in[11];
    const float* W1  = (const float*)d_in[12];
    const float* b1  = (const float*)d_in[13];
    const float* W2  = (const float*)d_in[14];
    const float* b2  = (const float*)d_in[15];
    const float* l2g = (const float*)d_in[16];
    const float* l2b = (const float*)d_in[17];
    float* outp = (float*)d_out;

    const size_t NE  = (size_t)MROWS * Dm;    // 4194304
    const size_t WDD = (size_t)Dm * Dm;
    const size_t WDF = (size_t)Dm * DFFn;
    const size_t WKV = 2 * WDD;               // concat KV slice [1024][512]

    float* xbuf = (float*)d_ws;               // NE f32
    float* ybuf = xbuf + NE;                  // NE f32
    float* t2   = ybuf + NE;                  // NE f32 (LN input temp)
    f16* xh  = (f16*)(t2 + NE);               // NE
    f16* yh  = xh + NE;                       // NE
    f16* R   = yh + NE;                       // 4*NE f16 region
    f16* qh  = R;                             // q(=k) heads f16
    f16* vt  = R + 2 * NE;                    // v transposed per head (fused)
    f16* t1h = R + 3 * NE;                    // attention output f16
    f16* fbh = R;                             // FFN hidden (aliases R, 4*NE)
    f16* wkvh = R + 4 * NE;                   // concat KV weights [6][1024][512]
    f16* woh = wkvh + 6 * WKV;
    f16* w1h = woh + 6 * WDD;                 // slots 0,1,3,5
    f16* w2h = w1h + 4 * WDF;
    float* bkv = (float*)(w2h + 4 * WDF);     // [6][1024] f32

    // ---- single prep launch: weight convert + bias concat + input copies
    PrepArgs pa;
    pa.Wk = Wk; pa.Wv = Wv; pa.Wo = Wo; pa.W1 = W1; pa.W2 = W2;
    pa.bk = bk; pa.bv = bv; pa.q_emb = q_emb; pa.qa_emb = qa_emb;
    pa.wkvh = wkvh; pa.woh = woh; pa.w1h = w1h; pa.w2h = w2h;
    pa.bkv = bkv; pa.xbuf = xbuf; pa.ybuf = ybuf; pa.xh = xh; pa.yh = yh;
    k_prep<<<45592, 256, 0, stream>>>(pa);

    // finalOut: if non-null, the LAST LayerNorm's f32 result goes there
    // (the f32 residual stream is dead afterwards; f16 mirror still written).
    auto layer = [&](int l, int maskflag, float* Xq, f16* Xqh, f16* Xvh,
                     bool apply_pos, float* finalOut) {
        if (Xqh == Xvh) {
            // fused KV projection: N=1024, 512 blocks (2/CU)
            k_gemm<0, 1, 2, 1, 128><<<dim3(1024 / 128, MROWS / 128), 256, 0, stream>>>(
                Xqh, wkvh + (size_t)l * WKV, bkv + l * 1024, (float*)vt, qh,
                MROWS, 1024, Dm, nullptr, nullptr);
        } else {
            // DUAL: K-proj of Xqh and V-proj of Xvh in one 512-block launch
            k_gemm<0, 1, 3, 1, 128><<<dim3(8, MROWS / 128), 256, 0, stream>>>(
                Xqh, wkvh + (size_t)l * WKV, bkv + l * 1024, nullptr, qh,
                MROWS, 512, Dm, Xvh, vt);
        }
        k_attn<<<Bsz * Hn * 32, 256, 0, stream>>>(qh, vt, t1h, gam + l * Hn, maskflag);
        // Wo GEMM: BM=64 -> 512 blocks (2/CU) instead of grid-limited 256
        k_gemm<0, 0, 0, 1, 64><<<dim3(Dm / 128, MROWS / 64), 256, 0, stream>>>(
            t1h, woh + (size_t)l * WDD, bo + l * Dm, t2, nullptr,
            MROWS, Dm, Dm, nullptr, nullptr);
        if (apply_pos) {
            k_ln<<<MROWS / 4, 256, 0, stream>>>(t2, Xq, l1g + l * Dm, l1b + l * Dm, Xq, Xqh);
            int sl = (l < 2) ? l : ((l + 1) >> 1);
            k_gemm<1, 1, 0, 0, 128><<<dim3(DFFn / 128, MROWS / 128), 256, 0, stream>>>(
                Xqh, w1h + (size_t)sl * WDF, b1 + l * DFFn, nullptr, fbh,
                MROWS, DFFn, Dm, nullptr, nullptr);
            // FFN2: BM=64 -> 512 blocks (2/CU)
            k_gemm<0, 0, 0, 1, 64><<<dim3(Dm / 128, MROWS / 64), 256, 0, stream>>>(
                fbh, w2h + (size_t)sl * WDF, b2 + l * Dm, t2, nullptr,
                MROWS, Dm, DFFn, nullptr, nullptr);
            k_ln<<<MROWS / 4, 256, 0, stream>>>(t2, Xq, l2g + l * Dm, l2b + l * Dm,
                                                finalOut ? finalOut : Xq, Xqh);
        } else {
            k_ln<<<MROWS / 4, 256, 0, stream>>>(t2, Xq, l1g + l * Dm, l1b + l * Dm,
                                                finalOut ? finalOut : Xq, Xqh);
        }
    };

    const size_t NEo = NE;
    // blocks_1: self-attn on y, mask=1, FFN. Layer 1 is y's final write -> out+NE.
    layer(0, 1, ybuf, yh, yh, true, nullptr);
    layer(1, 1, ybuf, yh, yh, true, outp + NEo);
    // blocks_2: (mask=1, no FFN) then (mask=0, values=y, FFN), twice.
    // Layer 5 is x's final write -> out.
    layer(2, 1, xbuf, xh, xh, false, nullptr);
    layer(3, 0, xbuf, xh, yh, true, nullptr);
    layer(4, 1, xbuf, xh, xh, false, nullptr);
    layer(5, 0, xbuf, xh, yh, true, outp);
}

// Round 11
// 1119.657 us; speedup vs baseline: 1.1050x; 1.0301x over previous
//
#include <hip/hip_runtime.h>
#include <hip/hip_bf16.h>

// Problem constants (AKT core): B=16, S=512, D=512, H=8, DFF=2048, NB=2, L=6
#define Bsz  16
#define Sl   512
#define Dm   512
#define Hn   8
#define DKh  64
#define DFFn 2048
#define MROWS (Bsz * Sl)      // 8192
#define NEGV (-1e32f)

typedef _Float16 f16;
typedef f16 f16x8 __attribute__((ext_vector_type(8)));
typedef f16 f16x4 __attribute__((ext_vector_type(4)));
typedef float f32x4 __attribute__((ext_vector_type(4)));

// async global->LDS, 16B per lane: lds dst = wave-uniform base + lane*16
#define GLDS16(g, l) __builtin_amdgcn_global_load_lds( \
    (const __attribute__((address_space(1))) void*)(g), \
    (__attribute__((address_space(3))) void*)(l), 16, 0, 0)

// ---------------------------------------------------------------------------
// k_prep: all one-off preprocessing in ONE launch.
// (f32 input copies dropped: xbuf/ybuf are write-before-read — first LN of
//  each stream takes its residual directly from q_emb/qa_emb.)
// ---------------------------------------------------------------------------
struct PrepArgs {
    const float *Wk, *Wv, *Wo, *W1, *W2, *bk, *bv, *q_emb, *qa_emb;
    f16 *wkvh, *woh, *w1h, *w2h;
    float *bkv;
    f16 *xh, *yh;
};

__device__ __forceinline__ void wconv_body(const float* src, f16* dst,
        int K, int N, int lmap, size_t zstride, int z, int nx, int ny,
        int t, float (*T)[36])
{
    int ls = lmap ? (z < 2 ? z : 2 * z - 1) : z;
    const float* S = src + (size_t)ls * K * N;
    f16* Dt = dst + (size_t)z * zstride;
    int n0 = nx * 32, k0 = ny * 32;
    int r = t >> 3, c = (t & 7) * 4;
    float4 v = *(const float4*)(S + (size_t)(k0 + r) * N + n0 + c);
    T[r][c] = v.x; T[r][c + 1] = v.y; T[r][c + 2] = v.z; T[r][c + 3] = v.w;
    __syncthreads();
    int n = t >> 3, kq = (t & 7) * 4;
    f16x4 o = { (f16)T[kq][n], (f16)T[kq + 1][n], (f16)T[kq + 2][n], (f16)T[kq + 3][n] };
    *(f16x4*)(Dt + (size_t)(n0 + n) * K + k0 + kq) = o;
}

__global__ __launch_bounds__(256) void k_prep(PrepArgs a)
{
    __shared__ float T[32][36];
    int id = blockIdx.x;
    int t = threadIdx.x;
    const size_t WDD = (size_t)Dm * Dm;
    const size_t WDF = (size_t)Dm * DFFn;
    const size_t WKV = 2 * WDD;

    if (id < 4608) {
        int which = id / 1536, rest = id % 1536;
        int z = rest >> 8, r2 = rest & 255;
        int nx = r2 & 15, ny = r2 >> 4;
        if (which == 0)      wconv_body(a.Wk, a.wkvh,       Dm, Dm, 0, WKV, z, nx, ny, t, T);
        else if (which == 1) wconv_body(a.Wv, a.wkvh + WDD, Dm, Dm, 0, WKV, z, nx, ny, t, T);
        else                 wconv_body(a.Wo, a.woh,        Dm, Dm, 0, WDD, z, nx, ny, t, T);
    } else if (id < 8704) {
        int id2 = id - 4608;
        int z = id2 >> 10, r2 = id2 & 1023;
        int nx = r2 & 63, ny = r2 >> 6;          // N=2048: 64 x-tiles, 16 y
        wconv_body(a.W1, a.w1h, Dm, DFFn, 1, WDF, z, nx, ny, t, T);
    } else if (id < 12800) {
        int id3 = id - 8704;
        int z = id3 >> 10, r2 = id3 & 1023;
        int nx = r2 & 15, ny = r2 >> 4;          // K=2048: 16 x, 64 y
        wconv_body(a.W2, a.w2h, DFFn, Dm, 1, WDF, z, nx, ny, t, T);
    } else if (id < 12824) {
        int i = (id - 12800) * 256 + t;          // 6*1024
        int z = i >> 10, c = i & 1023;
        a.bkv[i] = (c < 512) ? a.bk[z * 512 + c] : a.bv[z * 512 + c - 512];
    } else if (id < 16920) {
        // q_emb -> xh (f16 only), 4 elems/thread
        int i = (id - 12824) * 1024 + t * 4;
        float4 v = *(const float4*)(a.q_emb + i);
        f16x4 o = { (f16)v.x, (f16)v.y, (f16)v.z, (f16)v.w };
        *(f16x4*)(a.xh + i) = o;
    } else {
        // qa_emb -> yh (f16 only)
        int i = (id - 16920) * 1024 + t * 4;
        float4 v = *(const float4*)(a.qa_emb + i);
        f16x4 o = { (f16)v.x, (f16)v.y, (f16)v.z, (f16)v.w };
        *(f16x4*)(a.yh + i) = o;
    }
}

// ---------------------------------------------------------------------------
// MFMA f16 GEMM: C[M,N] = A[M,K] @ Bt[N,K]^T + bias[N]. A,Bt f16; bias f32.
// BM x 128 tile (BM=128 or 64), 4 waves (2x2, each BM/2 x 64), 16x16x32 MFMA.
// 2-buffer __syncthreads pipeline (proven). BM=64 (48KB LDS): grid-limited
// N=512 GEMMs -> 512 blocks = 2/CU (proven -37us r9).
// VTOUT=1: vt layout. VTOUT=2: fused KV N=1024. VTOUT=3: dual projections.
// ---------------------------------------------------------------------------
template <int RELU, int OUT16, int VTOUT, int BK64, int BM>
__global__ __launch_bounds__(256) void k_gemm(
    const f16* __restrict__ A, const f16* __restrict__ Bt,
    const float* __restrict__ bias, float* __restrict__ C, f16* __restrict__ Ch,
    int M, int N, int K,
    const f16* __restrict__ A2, f16* __restrict__ Ch2)
{
    constexpr int HL = BK64 ? 2 : 1;        // 32-wide halves per K-step
    constexpr int MI = BM / 32;             // i-frags per wave (4 or 2)
    constexpr int MW = BM / 2;              // wave M-extent
    constexpr int AHALF = BM * 32;          // f16 per A half-tile
    constexpr int ABUF = HL * AHALF;
    constexpr int BBUF = HL * 4096;
    __shared__ f16 As[2 * ABUF];
    __shared__ f16 Bs[2 * BBUF];
    int tid = threadIdx.x;
    int w = tid >> 6, lane = tid & 63;
    int ln = lane & 15, rg = lane >> 4;
    int wr = w >> 1, wc = w & 1;
    int m0 = blockIdx.y * BM;
    int half = (VTOUT == 3) ? (blockIdx.x >> 2) : 0;
    int n0 = (VTOUT == 3) ? (blockIdx.x & 3) * 128 : blockIdx.x * 128;

    const f16* Ause = (VTOUT == 3 && half) ? A2 : A;
    const f16* Btuse = (VTOUT == 3) ? Bt + (size_t)half * 512 * 512 : Bt;
    const float* biasuse = (VTOUT == 3) ? bias + half * 512 : bias;

    int s0 = tid, s1 = 256 + tid;
    int r0s = s0 >> 2, c0s = ((s0 & 3) ^ ((s0 >> 3) & 3));
    int r1s = s1 >> 2, c1s = ((s1 & 3) ^ ((s1 >> 3) & 3));

    const f16* a0 = Ause + (size_t)(m0 + r0s) * K + c0s * 8;
    const f16* a1 = Ause + (size_t)(m0 + (BM == 128 ? r1s : r0s)) * K
                    + (BM == 128 ? c1s : c0s) * 8;
    const f16* b0 = Btuse + (size_t)(n0 + r0s) * K + c0s * 8;
    const f16* b1 = Btuse + (size_t)(n0 + r1s) * K + c1s * 8;

    int cc8 = (rg ^ ((ln >> 1) & 3)) * 8;

    f32x4 acc[MI][4] = {};

    int nk = K >> (BK64 ? 6 : 5);

    auto STAGE = [&](int nb, int kt) {
        f16* lA = As + nb * ABUF + w * 512;
        f16* lB = Bs + nb * BBUF + w * 512;
#pragma unroll
        for (int hh = 0; hh < HL; ++hh) {
            GLDS16(a0 + kt + hh * 32, lA + hh * AHALF);
            if (BM == 128) GLDS16(a1 + kt + hh * 32, lA + hh * AHALF + 2048);
            GLDS16(b0 + kt + hh * 32, lB + hh * 4096);
            GLDS16(b1 + kt + hh * 32, lB + hh * 4096 + 2048);
        }
    };

    auto COMPUTE = [&](int nb) {
#pragma unroll
        for (int hh = 0; hh < HL; ++hh) {
            const f16* Ab = As + nb * ABUF + hh * AHALF;
            const f16* Bb = Bs + nb * BBUF + hh * 4096;
            f16x8 af[MI], bf[4];
#pragma unroll
            for (int i = 0; i < MI; ++i) {
                int m = wr * MW + i * 16 + ln;
                af[i] = *(const f16x8*)(Ab + m * 32 + cc8);
            }
#pragma unroll
            for (int j = 0; j < 4; ++j) {
                int nn = wc * 64 + j * 16 + ln;
                bf[j] = *(const f16x8*)(Bb + nn * 32 + cc8);
            }
#pragma unroll
            for (int i = 0; i < MI; ++i)
#pragma unroll
                for (int j = 0; j < 4; ++j)
                    acc[i][j] = __builtin_amdgcn_mfma_f32_16x16x32_f16(af[i], bf[j], acc[i][j], 0, 0, 0);
        }
    };

    STAGE(0, 0);
    __syncthreads();   // vmcnt(0) drain: buf0 ready
    int cur = 0;
    for (int t = 0; t < nk; ++t) {
        if (t + 1 < nk) STAGE(cur ^ 1, (t + 1) << (BK64 ? 6 : 5));
        COMPUTE(cur);
        __syncthreads();   // drains vmcnt(0): next buffer staged, reads done
        cur ^= 1;
    }

#pragma unroll
    for (int j = 0; j < 4; ++j) {
        int col = n0 + wc * 64 + j * 16 + ln;
        float bj = biasuse[col];
#pragma unroll
        for (int i = 0; i < MI; ++i) {
            int rb = m0 + wr * MW + i * 16 + rg * 4;
            if constexpr (VTOUT == 1) {
                int bq = rb >> 9, s = rb & 511;
                int hh = col >> 6, dk = col & 63;
                f16x4 o;
#pragma unroll
                for (int r = 0; r < 4; ++r) o[r] = (f16)(acc[i][j][r] + bj);
                *(f16x4*)(Ch + (((size_t)(bq * 8 + hh) * 64 + dk) << 9) + s) = o;
            } else if constexpr (VTOUT == 2) {
                if (n0 < 512) {       // qh half (block-uniform branch)
#pragma unroll
                    for (int r = 0; r < 4; ++r)
                        Ch[(size_t)(rb + r) * 512 + col] = (f16)(acc[i][j][r] + bj);
                } else {              // vt half
                    f16* Cv = (f16*)C;
                    int colv = col - 512;
                    int bq = rb >> 9, s = rb & 511;
                    int hh = colv >> 6, dk = colv & 63;
                    f16x4 o;
#pragma unroll
                    for (int r = 0; r < 4; ++r) o[r] = (f16)(acc[i][j][r] + bj);
                    *(f16x4*)(Cv + (((size_t)(bq * 8 + hh) * 64 + dk) << 9) + s) = o;
                }
            } else if constexpr (VTOUT == 3) {
                if (half == 0) {      // qh
#pragma unroll
                    for (int r = 0; r < 4; ++r)
                        Ch[(size_t)(rb + r) * 512 + col] = (f16)(acc[i][j][r] + bj);
                } else {              // vt
                    int bq = rb >> 9, s = rb & 511;
                    int hh = col >> 6, dk = col & 63;
                    f16x4 o;
#pragma unroll
                    for (int r = 0; r < 4; ++r) o[r] = (f16)(acc[i][j][r] + bj);
                    *(f16x4*)(Ch2 + (((size_t)(bq * 8 + hh) * 64 + dk) << 9) + s) = o;
                }
            } else {
#pragma unroll
                for (int r = 0; r < 4; ++r) {
                    float v = acc[i][j][r] + bj;
                    if (RELU) v = fmaxf(v, 0.f);
                    if (OUT16) Ch[(size_t)(rb + r) * N + col] = (f16)v;
                    else       C [(size_t)(rb + r) * N + col] = v;
                }
            }
        }
    }
}

// ---------------------------------------------------------------------------
// AKT attention body, specialized on JTC. (Unchanged from round 7.)
// ---------------------------------------------------------------------------
template <int JTC>
__device__ __forceinline__ void attn_body(
    float (*Sc)[516], f16* Ph, const f16* Qbase, const f16* vbase, f16* ob,
    f16x8 aq0, f16x8 aq1, float g,
    int w, int lane, int ln, int rg, int i0, int maskflag)
{
    // ---- Phase 1: scores, 16-col unit granularity across waves ----------
#pragma unroll
    for (int ui = 0; ui < JTC; ++ui) {
        int u = w + ui * 4;
        const f16* kb = Qbase + (size_t)(u * 16 + ln) * Dm + rg * 8;
        f16x8 b0 = *(const f16x8*)(kb);
        f16x8 b1 = *(const f16x8*)(kb + 32);
        f32x4 c = {};
        c = __builtin_amdgcn_mfma_f32_16x16x32_f16(aq0, b0, c, 0, 0, 0);
        c = __builtin_amdgcn_mfma_f32_16x16x32_f16(aq1, b1, c, 0, 0, 0);
#pragma unroll
        for (int r = 0; r < 4; ++r)
            Sc[rg * 4 + r][u * 16 + ln] = c[r];
    }
    __syncthreads();

    int jbase = lane * JTC;
    int im = i0 + w * 4;

    // ---- loop A: vector-read scores -> regs, mask+scale, first exp-sums -
    float ss[4][JTC];
    float run[4];
#pragma unroll
    for (int q = 0; q < 4; ++q) {
        const float* Srow = &Sc[w * 4 + q][0];
        if constexpr (JTC == 8) {
            float4 t0 = *(const float4*)(Srow + jbase);
            float4 t1 = *(const float4*)(Srow + jbase + 4);
            ss[q][0] = t0.x; ss[q][1] = t0.y; ss[q][2] = t0.z; ss[q][3] = t0.w;
            ss[q][4] = t1.x; ss[q][5] = t1.y; ss[q][6] = t1.z; ss[q][7] = t1.w;
        } else if constexpr (JTC == 4) {
            float4 t0 = *(const float4*)(Srow + jbase);
            ss[q][0] = t0.x; ss[q][1] = t0.y; ss[q][2] = t0.z; ss[q][3] = t0.w;
        } else {
#pragma unroll
            for (int k = 0; k < JTC; ++k) ss[q][k] = Srow[jbase + k];
        }
        int jmax = maskflag ? (im + q) : (im + q - 1);
        float acc = 0.f;
#pragma unroll
        for (int k = 0; k < JTC; ++k) {
            int j = jbase + k;
            float s = (j <= jmax) ? ss[q][k] * 0.125f : NEGV;
            ss[q][k] = s;
            acc += __expf(s);              // exp(-1e32) = 0 for masked
        }
        run[q] = acc;
    }
    // 4 interleaved inclusive scans across lanes (j-ordered)
    float sl[4] = { run[0], run[1], run[2], run[3] };
#pragma unroll
    for (int off = 1; off < 64; off <<= 1) {
        float n0 = __shfl_up(sl[0], off);
        float n1 = __shfl_up(sl[1], off);
        float n2 = __shfl_up(sl[2], off);
        float n3 = __shfl_up(sl[3], off);
        if (lane >= off) { sl[0] += n0; sl[1] += n1; sl[2] += n2; sl[3] += n3; }
    }

    // ---- loop B: LDS-free decay + second softmax (unnormalized) ---------
    float Z2[4];
#pragma unroll
    for (int q = 0; q < 4; ++q) {
        float excl = sl[q] - run[q];
        float Z = __shfl(sl[q], 63);
        float inv = 1.f / Z;
        int i = im + q;
        float csum = 0.f, z2 = 0.f;
#pragma unroll
        for (int k = 0; k < JTC; ++k) {
            int j = jbase + k;
            float s = ss[q][k];
            csum += __expf(s);                       // inclusive cumsum
            float rem = (Z - excl - csum) * inv;     // disttot - distcum
            float pos = fabsf((float)(i - j));
            float dd = fmaxf(rem * pos, 0.f);        // fmax(NaN,0)=0 safe
            float te = __expf(sqrtf(dd) * g);
            te = fminf(fmaxf(te, 1e-5f), 1e5f);
            float pe2 = __expf(s * te);              // masked: -1e32*te -> 0
            ss[q][k] = pe2;
            z2 += pe2;
        }
        Z2[q] = z2;
    }
    // 4 interleaved sum reductions
#pragma unroll
    for (int off = 32; off >= 1; off >>= 1) {
        Z2[0] += __shfl_xor(Z2[0], off);
        Z2[1] += __shfl_xor(Z2[1], off);
        Z2[2] += __shfl_xor(Z2[2], off);
        Z2[3] += __shfl_xor(Z2[3], off);
    }
    __syncthreads();   // ALL waves' Sc reads done; Ph may now overwrite Sc

    // ---- write normalized P f16 into swizzled Ph ------------------------
#pragma unroll
    for (int q = 0; q < 4; ++q) {
        int r = w * 4 + q;
        float inv2 = 1.f / Z2[q];
        int zp = (maskflag == 0) && (im + q == 0);
        if constexpr (JTC == 8) {
            int slot = (lane & ~7) | ((lane & 7) ^ (r & 7));
            f16x8 o8;
#pragma unroll
            for (int k = 0; k < 8; ++k)
                o8[k] = (f16)(zp ? 0.f : ss[q][k] * inv2);
            *(f16x8*)(Ph + r * 512 + slot * 8) = o8;
        } else if constexpr (JTC == 4) {
            int cj = lane >> 1;
            int slot = (cj & ~7) | ((cj & 7) ^ (r & 7));
            f16x4 o4;
#pragma unroll
            for (int k = 0; k < 4; ++k)
                o4[k] = (f16)(zp ? 0.f : ss[q][k] * inv2);
            *(f16x4*)(Ph + r * 512 + slot * 8 + (lane & 1) * 4) = o4;
        } else {
#pragma unroll
            for (int k = 0; k < JTC; ++k) {
                int j = jbase + k;
                int cj = j >> 3;
                int slot = (cj & ~7) | ((cj & 7) ^ (r & 7));
                Ph[r * 512 + slot * 8 + (j & 7)] =
                    (f16)(zp ? 0.f : ss[q][k] * inv2);
            }
        }
    }
    __syncthreads();

    // ---- Phase 3: O = P @ V, dual accumulator ---------------------------
    f32x4 oa0 = {}, oa1 = {};
#pragma unroll
    for (int f = 0; f < 2 * JTC; ++f) {
        f16x8 bv = *(const f16x8*)(vbase + (f >> 1) * 64 + (f & 1) * 32);
        int c = (f >> 1) * 8 + (f & 1) * 4 + rg;
        int slot = (c & ~7) | ((c & 7) ^ (ln & 7));
        f16x8 ap = *(const f16x8*)(Ph + ln * 512 + slot * 8);
        if (f & 1) oa1 = __builtin_amdgcn_mfma_f32_16x16x32_f16(ap, bv, oa1, 0, 0, 0);
        else       oa0 = __builtin_amdgcn_mfma_f32_16x16x32_f16(ap, bv, oa0, 0, 0, 0);
    }
    f32x4 oa = oa0 + oa1;
#pragma unroll
    for (int r = 0; r < 4; ++r)
        ob[(size_t)r * Dm] = (f16)oa[r];
}

// ---------------------------------------------------------------------------
// AKT attention. One block per (b, h, 16-row i-tile), 4 waves.
// XCD-chunked swizzle (proven). Heavy-first LPT order.
// ---------------------------------------------------------------------------
__global__ __launch_bounds__(256, 4) void k_attn(
    const f16* __restrict__ Qh, const f16* __restrict__ VT,
    f16* __restrict__ O, const float* __restrict__ gam, int maskflag)
{
    __shared__ float Sc[16][516];
    f16* Ph = (f16*)Sc;          // 16KB alias, safe after post-read barrier

    int tid = threadIdx.x;
    int w = tid >> 6, lane = tid & 63;
    int ln = lane & 15, rg = lane >> 4;

    // XCD-chunked bijective remap (4096 blocks, 8 XCDs, 512 each)
    int bid = blockIdx.x;
    int lbid = (bid & 7) * 512 + (bid >> 3);
    int tile = 31 - (lbid & 31);        // heavy-first within each bh
    int bh = lbid >> 5;
    int b = bh >> 3, h = bh & 7;
    int i0 = tile * 16;
    int jtc = (tile >> 2) + 1;          // valid j-tiles (64 cols each)

    const f16* Qbase = Qh + ((size_t)b * Sl) * Dm + h * DKh;
    const f16* vbase = VT + ((size_t)bh * 64 + w * 16 + ln) * 512 + rg * 8;
    f16* ob = O + ((size_t)b * Sl + i0 + rg * 4) * Dm + h * DKh + w * 16 + ln;

    float gm = gam[h];
    float g = -((gm > 20.f) ? gm : log1pf(__expf(gm)));   // -softplus(gamma)

    // A-frags: Q rows i0..i0+15, reused across units
    f16x8 aq0 = *(const f16x8*)(Qbase + (size_t)(i0 + ln) * Dm + rg * 8);
    f16x8 aq1 = *(const f16x8*)(Qbase + (size_t)(i0 + ln) * Dm + 32 + rg * 8);

    switch (jtc) {
    case 1: attn_body<1>(Sc, Ph, Qbase, vbase, ob, aq0, aq1, g, w, lane, ln, rg, i0, maskflag); break;
    case 2: attn_body<2>(Sc, Ph, Qbase, vbase, ob, aq0, aq1, g, w, lane, ln, rg, i0, maskflag); break;
    case 3: attn_body<3>(Sc, Ph, Qbase, vbase, ob, aq0, aq1, g, w, lane, ln, rg, i0, maskflag); break;
    case 4: attn_body<4>(Sc, Ph, Qbase, vbase, ob, aq0, aq1, g, w, lane, ln, rg, i0, maskflag); break;
    case 5: attn_body<5>(Sc, Ph, Qbase, vbase, ob, aq0, aq1, g, w, lane, ln, rg, i0, maskflag); break;
    case 6: attn_body<6>(Sc, Ph, Qbase, vbase, ob, aq0, aq1, g, w, lane, ln, rg, i0, maskflag); break;
    case 7: attn_body<7>(Sc, Ph, Qbase, vbase, ob, aq0, aq1, g, w, lane, ln, rg, i0, maskflag); break;
    default: attn_body<8>(Sc, Ph, Qbase, vbase, ob, aq0, aq1, g, w, lane, ln, rg, i0, maskflag); break;
    }
}

// ---------------------------------------------------------------------------
// Residual + LayerNorm: Out = LN(Xn_f16 + Rr)*g + b, dual f32+f16 output.
// Xn is f16 (GEMM emits f16 intermediate -> halves t2 read+write traffic).
// ---------------------------------------------------------------------------
__global__ __launch_bounds__(256) void k_ln(
    const f16* __restrict__ Xn, const float* __restrict__ Rr,
    const float* __restrict__ gw, const float* __restrict__ bw,
    float* __restrict__ Out, f16* __restrict__ Outh)
{
    int tid = threadIdx.x;
    int w = tid >> 6, lane = tid & 63;
    int row = blockIdx.x * 4 + w;
    const f16* xr = Xn + (size_t)row * Dm;
    const float* rr = Rr + (size_t)row * Dm;
    int c0 = lane * 4, c1 = 256 + lane * 4;
    f16x4 xa = *(const f16x4*)(xr + c0);
    f16x4 xb = *(const f16x4*)(xr + c1);
    float4 ra = *(const float4*)(rr + c0);
    float4 rb = *(const float4*)(rr + c1);
    float4 va, vb;
    va.x = (float)xa[0] + ra.x; va.y = (float)xa[1] + ra.y;
    va.z = (float)xa[2] + ra.z; va.w = (float)xa[3] + ra.w;
    vb.x = (float)xb[0] + rb.x; vb.y = (float)xb[1] + rb.y;
    vb.z = (float)xb[2] + rb.z; vb.w = (float)xb[3] + rb.w;
    float sum = va.x + va.y + va.z + va.w + vb.x + vb.y + vb.z + vb.w;
#pragma unroll
    for (int off = 32; off >= 1; off >>= 1) sum += __shfl_xor(sum, off);
    float mu = sum * (1.f / 512.f);
    float var = 0.f;
    {
        float d;
        d = va.x - mu; var += d * d;  d = va.y - mu; var += d * d;
        d = va.z - mu; var += d * d;  d = va.w - mu; var += d * d;
        d = vb.x - mu; var += d * d;  d = vb.y - mu; var += d * d;
        d = vb.z - mu; var += d * d;  d = vb.w - mu; var += d * d;
    }
#pragma unroll
    for (int off = 32; off >= 1; off >>= 1) var += __shfl_xor(var, off);
    float rs = rsqrtf(var * (1.f / 512.f) + 1e-5f);
    float4 ga = *(const float4*)(gw + c0);
    float4 gb = *(const float4*)(gw + c1);
    float4 ba = *(const float4*)(bw + c0);
    float4 bb = *(const float4*)(bw + c1);
    float4 oa, ob;
    oa.x = (va.x - mu) * rs * ga.x + ba.x;  oa.y = (va.y - mu) * rs * ga.y + ba.y;
    oa.z = (va.z - mu) * rs * ga.z + ba.z;  oa.w = (va.w - mu) * rs * ga.w + ba.w;
    ob.x = (vb.x - mu) * rs * gb.x + bb.x;  ob.y = (vb.y - mu) * rs * gb.y + bb.y;
    ob.z = (vb.z - mu) * rs * gb.z + bb.z;  ob.w = (vb.w - mu) * rs * gb.w + bb.w;
    float* orow = Out + (size_t)row * Dm;
    f16* ohrow = Outh + (size_t)row * Dm;
    *(float4*)(orow + c0) = oa;
    *(float4*)(orow + c1) = ob;
    f16x4 ha = { (f16)oa.x, (f16)oa.y, (f16)oa.z, (f16)oa.w };
    f16x4 hb = { (f16)ob.x, (f16)ob.y, (f16)ob.z, (f16)ob.w };
    *(f16x4*)(ohrow + c0) = ha;
    *(f16x4*)(ohrow + c1) = hb;
}

// ---------------------------------------------------------------------------
extern "C" void kernel_launch(void* const* d_in, const int* in_sizes, int n_in,
                              void* d_out, int out_size, void* d_ws, size_t ws_size,
                              hipStream_t stream)
{
    const float* q_emb  = (const float*)d_in[0];
    const float* qa_emb = (const float*)d_in[1];
    const float* Wk  = (const float*)d_in[3];
    const float* bk  = (const float*)d_in[4];
    const float* Wv  = (const float*)d_in[5];
    const float* bv  = (const float*)d_in[6];
    const float* Wo  = (const float*)d_in[7];
    const float* bo  = (const float*)d_in[8];
    const float* gam = (const float*)d_in[9];
    const float* l1g = (const float*)d_in[10];
    const float* l1b = (const float*)d_in[11];
    const float* W1  = (const float*)d_in[12];
    const float* b1  = (const float*)d_in[13];
    const float* W2  = (const float*)d_in[14];
    const float* b2  = (const float*)d_in[15];
    const float* l2g = (const float*)d_in[16];
    const float* l2b = (const float*)d_in[17];
    float* outp = (float*)d_out;

    const size_t NE  = (size_t)MROWS * Dm;    // 4194304
    const size_t WDD = (size_t)Dm * Dm;
    const size_t WDF = (size_t)Dm * DFFn;
    const size_t WKV = 2 * WDD;               // concat KV slice [1024][512]

    float* xbuf = (float*)d_ws;               // NE f32 (residual stream x)
    float* ybuf = xbuf + NE;                  // NE f32 (residual stream y)
    float* t2   = ybuf + NE;                  // NE f32 region; f16 alias below
    f16* t2h = (f16*)t2;                      // f16 GEMM->LN intermediate
    f16* xh  = (f16*)(t2 + NE);               // NE
    f16* yh  = xh + NE;                       // NE
    f16* R   = yh + NE;                       // 4*NE f16 region
    f16* qh  = R;                             // q(=k) heads f16
    f16* vt  = R + 2 * NE;                    // v transposed per head (fused)
    f16* t1h = R + 3 * NE;                    // attention output f16
    f16* fbh = R;                             // FFN hidden (aliases R, 4*NE)
    f16* wkvh = R + 4 * NE;                   // concat KV weights [6][1024][512]
    f16* woh = wkvh + 6 * WKV;
    f16* w1h = woh + 6 * WDD;                 // slots 0,1,3,5
    f16* w2h = w1h + 4 * WDF;
    float* bkv = (float*)(w2h + 4 * WDF);     // [6][1024] f32

    // ---- single prep launch: weight convert + bias concat + f16 input conv
    PrepArgs pa;
    pa.Wk = Wk; pa.Wv = Wv; pa.Wo = Wo; pa.W1 = W1; pa.W2 = W2;
    pa.bk = bk; pa.bv = bv; pa.q_emb = q_emb; pa.qa_emb = qa_emb;
    pa.wkvh = wkvh; pa.woh = woh; pa.w1h = w1h; pa.w2h = w2h;
    pa.bkv = bkv; pa.xh = xh; pa.yh = yh;
    k_prep<<<21016, 256, 0, stream>>>(pa);

    // rIn: residual source for the FIRST LN of this layer (raw embedding
    // for each stream's first layer -> xbuf/ybuf become write-before-read).
    // finalOut: the LAST LN's f32 result goes to the output buffer.
    auto layer = [&](int l, int maskflag, float* Xq, f16* Xqh, f16* Xvh,
                     bool apply_pos, const float* rIn, float* finalOut) {
        if (Xqh == Xvh) {
            // fused KV projection: N=1024, 512 blocks (2/CU)
            k_gemm<0, 1, 2, 1, 128><<<dim3(1024 / 128, MROWS / 128), 256, 0, stream>>>(
                Xqh, wkvh + (size_t)l * WKV, bkv + l * 1024, (float*)vt, qh,
                MROWS, 1024, Dm, nullptr, nullptr);
        } else {
            // DUAL: K-proj of Xqh and V-proj of Xvh in one 512-block launch
            k_gemm<0, 1, 3, 1, 128><<<dim3(8, MROWS / 128), 256, 0, stream>>>(
                Xqh, wkvh + (size_t)l * WKV, bkv + l * 1024, nullptr, qh,
                MROWS, 512, Dm, Xvh, vt);
        }
        k_attn<<<Bsz * Hn * 32, 256, 0, stream>>>(qh, vt, t1h, gam + l * Hn, maskflag);
        // Wo GEMM: BM=64 (512 blocks, 2/CU), f16 output -> t2h
        k_gemm<0, 1, 0, 1, 64><<<dim3(Dm / 128, MROWS / 64), 256, 0, stream>>>(
            t1h, woh + (size_t)l * WDD, bo + l * Dm, nullptr, t2h,
            MROWS, Dm, Dm, nullptr, nullptr);
        if (apply_pos) {
            k_ln<<<MROWS / 4, 256, 0, stream>>>(t2h, rIn, l1g + l * Dm, l1b + l * Dm, Xq, Xqh);
            int sl = (l < 2) ? l : ((l + 1) >> 1);
            k_gemm<1, 1, 0, 0, 128><<<dim3(DFFn / 128, MROWS / 128), 256, 0, stream>>>(
                Xqh, w1h + (size_t)sl * WDF, b1 + l * DFFn, nullptr, fbh,
                MROWS, DFFn, Dm, nullptr, nullptr);
            // FFN2: BM=64, f16 output -> t2h
            k_gemm<0, 1, 0, 1, 64><<<dim3(Dm / 128, MROWS / 64), 256, 0, stream>>>(
                fbh, w2h + (size_t)sl * WDF, b2 + l * Dm, nullptr, t2h,
                MROWS, Dm, DFFn, nullptr, nullptr);
            k_ln<<<MROWS / 4, 256, 0, stream>>>(t2h, Xq, l2g + l * Dm, l2b + l * Dm,
                                                finalOut ? finalOut : Xq, Xqh);
        } else {
            k_ln<<<MROWS / 4, 256, 0, stream>>>(t2h, rIn, l1g + l * Dm, l1b + l * Dm,
                                                finalOut ? finalOut : Xq, Xqh);
        }
    };

    const size_t NEo = NE;
    // blocks_1: self-attn on y, mask=1, FFN. Layer 1 is y's final write -> out+NE.
    layer(0, 1, ybuf, yh, yh, true, qa_emb, nullptr);
    layer(1, 1, ybuf, yh, yh, true, ybuf, outp + NEo);
    // blocks_2: (mask=1, no FFN) then (mask=0, values=y, FFN), twice.
    // Layer 5 is x's final write -> out.
    layer(2, 1, xbuf, xh, xh, false, q_emb, nullptr);
    layer(3, 0, xbuf, xh, yh, true, xbuf, nullptr);
    layer(4, 1, xbuf, xh, xh, false, xbuf, nullptr);
    layer(5, 0, xbuf, xh, yh, true, xbuf, outp);
}

// Round 12
// 1023.934 us; speedup vs baseline: 1.2083x; 1.0935x over previous
//
#include <hip/hip_runtime.h>
#include <hip/hip_bf16.h>

// Problem constants (AKT core): B=16, S=512, D=512, H=8, DFF=2048, NB=2, L=6
#define Bsz  16
#define Sl   512
#define Dm   512
#define Hn   8
#define DKh  64
#define DFFn 2048
#define MROWS (Bsz * Sl)      // 8192
#define NEGV (-1e32f)

typedef _Float16 f16;
typedef f16 f16x8 __attribute__((ext_vector_type(8)));
typedef f16 f16x4 __attribute__((ext_vector_type(4)));
typedef float f32x4 __attribute__((ext_vector_type(4)));

// async global->LDS, 16B per lane: lds dst = wave-uniform base + lane*16
#define GLDS16(g, l) __builtin_amdgcn_global_load_lds( \
    (const __attribute__((address_space(1))) void*)(g), \
    (__attribute__((address_space(3))) void*)(l), 16, 0, 0)

// ---------------------------------------------------------------------------
// k_prep: all one-off preprocessing in ONE launch.
// ---------------------------------------------------------------------------
struct PrepArgs {
    const float *Wk, *Wv, *Wo, *W1, *W2, *bk, *bv, *q_emb, *qa_emb;
    f16 *wkvh, *woh, *w1h, *w2h;
    float *bkv;
    f16 *xh, *yh;
};

__device__ __forceinline__ void wconv_body(const float* src, f16* dst,
        int K, int N, int lmap, size_t zstride, int z, int nx, int ny,
        int t, float (*T)[36])
{
    int ls = lmap ? (z < 2 ? z : 2 * z - 1) : z;
    const float* S = src + (size_t)ls * K * N;
    f16* Dt = dst + (size_t)z * zstride;
    int n0 = nx * 32, k0 = ny * 32;
    int r = t >> 3, c = (t & 7) * 4;
    float4 v = *(const float4*)(S + (size_t)(k0 + r) * N + n0 + c);
    T[r][c] = v.x; T[r][c + 1] = v.y; T[r][c + 2] = v.z; T[r][c + 3] = v.w;
    __syncthreads();
    int n = t >> 3, kq = (t & 7) * 4;
    f16x4 o = { (f16)T[kq][n], (f16)T[kq + 1][n], (f16)T[kq + 2][n], (f16)T[kq + 3][n] };
    *(f16x4*)(Dt + (size_t)(n0 + n) * K + k0 + kq) = o;
}

__global__ __launch_bounds__(256) void k_prep(PrepArgs a)
{
    __shared__ float T[32][36];
    int id = blockIdx.x;
    int t = threadIdx.x;
    const size_t WDD = (size_t)Dm * Dm;
    const size_t WDF = (size_t)Dm * DFFn;
    const size_t WKV = 2 * WDD;

    if (id < 4608) {
        int which = id / 1536, rest = id % 1536;
        int z = rest >> 8, r2 = rest & 255;
        int nx = r2 & 15, ny = r2 >> 4;
        if (which == 0)      wconv_body(a.Wk, a.wkvh,       Dm, Dm, 0, WKV, z, nx, ny, t, T);
        else if (which == 1) wconv_body(a.Wv, a.wkvh + WDD, Dm, Dm, 0, WKV, z, nx, ny, t, T);
        else                 wconv_body(a.Wo, a.woh,        Dm, Dm, 0, WDD, z, nx, ny, t, T);
    } else if (id < 8704) {
        int id2 = id - 4608;
        int z = id2 >> 10, r2 = id2 & 1023;
        int nx = r2 & 63, ny = r2 >> 6;          // N=2048: 64 x-tiles, 16 y
        wconv_body(a.W1, a.w1h, Dm, DFFn, 1, WDF, z, nx, ny, t, T);
    } else if (id < 12800) {
        int id3 = id - 8704;
        int z = id3 >> 10, r2 = id3 & 1023;
        int nx = r2 & 15, ny = r2 >> 4;          // K=2048: 16 x, 64 y
        wconv_body(a.W2, a.w2h, DFFn, Dm, 1, WDF, z, nx, ny, t, T);
    } else if (id < 12824) {
        int i = (id - 12800) * 256 + t;          // 6*1024
        int z = i >> 10, c = i & 1023;
        a.bkv[i] = (c < 512) ? a.bk[z * 512 + c] : a.bv[z * 512 + c - 512];
    } else if (id < 16920) {
        // q_emb -> xh (f16 only), 4 elems/thread
        int i = (id - 12824) * 1024 + t * 4;
        float4 v = *(const float4*)(a.q_emb + i);
        f16x4 o = { (f16)v.x, (f16)v.y, (f16)v.z, (f16)v.w };
        *(f16x4*)(a.xh + i) = o;
    } else {
        // qa_emb -> yh (f16 only)
        int i = (id - 16920) * 1024 + t * 4;
        float4 v = *(const float4*)(a.qa_emb + i);
        f16x4 o = { (f16)v.x, (f16)v.y, (f16)v.z, (f16)v.w };
        *(f16x4*)(a.yh + i) = o;
    }
}

// ---------------------------------------------------------------------------
// MFMA f16 GEMM: C[M,N] = A[M,K] @ Bt[N,K]^T + bias[N]. A,Bt f16; bias f32.
// BM x 128 tile (BM=128 or 64), 4 waves (2x2, each BM/2 x 64), 16x16x32 MFMA.
// DEEP=0: 2-buffer __syncthreads pipeline (proven).
// DEEP=1 (BM=64+BK64 only): 3-buffer counted-vmcnt pipeline, prefetch dist 2.
//   72KB LDS -> still 2 blocks/CU (grid 512 = 2/CU anyway) — retries r8's
//   T3/T4 schedule WITHOUT the occupancy confound (r8: 96KB -> 1/CU, lost).
//   STAGE = 6 GLDS16/wave at BM64 -> s_waitcnt vmcnt(6) completes exactly
//   the K-step-ahead buffer while the newest STAGE stays in flight. Bias
//   preloaded + vmcnt(0)-drained BEFORE staging so counts are exact.
// VTOUT=1: vt layout. VTOUT=2: fused KV N=1024. VTOUT=3: dual projections.
// ---------------------------------------------------------------------------
template <int RELU, int OUT16, int VTOUT, int BK64, int BM, int DEEP>
__global__ __launch_bounds__(256) void k_gemm(
    const f16* __restrict__ A, const f16* __restrict__ Bt,
    const float* __restrict__ bias, float* __restrict__ C, f16* __restrict__ Ch,
    int M, int N, int K,
    const f16* __restrict__ A2, f16* __restrict__ Ch2)
{
    constexpr int HL = BK64 ? 2 : 1;        // 32-wide halves per K-step
    constexpr int MI = BM / 32;             // i-frags per wave (4 or 2)
    constexpr int MW = BM / 2;              // wave M-extent
    constexpr int AHALF = BM * 32;          // f16 per A half-tile
    constexpr int ABUF = HL * AHALF;
    constexpr int BBUF = HL * 4096;
    constexpr int NBUF = DEEP ? 3 : 2;
    __shared__ f16 As[NBUF * ABUF];
    __shared__ f16 Bs[NBUF * BBUF];
    int tid = threadIdx.x;
    int w = tid >> 6, lane = tid & 63;
    int ln = lane & 15, rg = lane >> 4;
    int wr = w >> 1, wc = w & 1;
    int m0 = blockIdx.y * BM;
    int half = (VTOUT == 3) ? (blockIdx.x >> 2) : 0;
    int n0 = (VTOUT == 3) ? (blockIdx.x & 3) * 128 : blockIdx.x * 128;

    const f16* Ause = (VTOUT == 3 && half) ? A2 : A;
    const f16* Btuse = (VTOUT == 3) ? Bt + (size_t)half * 512 * 512 : Bt;
    const float* biasuse = (VTOUT == 3) ? bias + half * 512 : bias;

    // bias preload; for DEEP must complete before staging (exact vmcnt counts)
    float bj4[4];
#pragma unroll
    for (int j = 0; j < 4; ++j)
        bj4[j] = biasuse[n0 + wc * 64 + j * 16 + ln];
    if (DEEP) asm volatile("s_waitcnt vmcnt(0) lgkmcnt(0)" ::: "memory");

    int s0 = tid, s1 = 256 + tid;
    int r0s = s0 >> 2, c0s = ((s0 & 3) ^ ((s0 >> 3) & 3));
    int r1s = s1 >> 2, c1s = ((s1 & 3) ^ ((s1 >> 3) & 3));

    const f16* a0 = Ause + (size_t)(m0 + r0s) * K + c0s * 8;
    const f16* a1 = Ause + (size_t)(m0 + (BM == 128 ? r1s : r0s)) * K
                    + (BM == 128 ? c1s : c0s) * 8;
    const f16* b0 = Btuse + (size_t)(n0 + r0s) * K + c0s * 8;
    const f16* b1 = Btuse + (size_t)(n0 + r1s) * K + c1s * 8;

    int cc8 = (rg ^ ((ln >> 1) & 3)) * 8;

    f32x4 acc[MI][4] = {};

    int nk = K >> (BK64 ? 6 : 5);

    auto STAGE = [&](int nb, int kt) {
        f16* lA = As + nb * ABUF + w * 512;
        f16* lB = Bs + nb * BBUF + w * 512;
#pragma unroll
        for (int hh = 0; hh < HL; ++hh) {
            GLDS16(a0 + kt + hh * 32, lA + hh * AHALF);
            if (BM == 128) GLDS16(a1 + kt + hh * 32, lA + hh * AHALF + 2048);
            GLDS16(b0 + kt + hh * 32, lB + hh * 4096);
            GLDS16(b1 + kt + hh * 32, lB + hh * 4096 + 2048);
        }
    };

    auto COMPUTE = [&](int nb) {
#pragma unroll
        for (int hh = 0; hh < HL; ++hh) {
            const f16* Ab = As + nb * ABUF + hh * AHALF;
            const f16* Bb = Bs + nb * BBUF + hh * 4096;
            f16x8 af[MI], bf[4];
#pragma unroll
            for (int i = 0; i < MI; ++i) {
                int m = wr * MW + i * 16 + ln;
                af[i] = *(const f16x8*)(Ab + m * 32 + cc8);
            }
#pragma unroll
            for (int j = 0; j < 4; ++j) {
                int nn = wc * 64 + j * 16 + ln;
                bf[j] = *(const f16x8*)(Bb + nn * 32 + cc8);
            }
#pragma unroll
            for (int i = 0; i < MI; ++i)
#pragma unroll
                for (int j = 0; j < 4; ++j)
                    acc[i][j] = __builtin_amdgcn_mfma_f32_16x16x32_f16(af[i], bf[j], acc[i][j], 0, 0, 0);
        }
    };

    if constexpr (DEEP) {
        // 3-buffer deep pipeline, prefetch distance 2, counted vmcnt(6)
        STAGE(0, 0);
        STAGE(1, 64);
        asm volatile("s_waitcnt vmcnt(6)" ::: "memory");   // buf0 ready
        __builtin_amdgcn_s_barrier();
        int cur = 0;
        for (int t = 0; t < nk; ++t) {
            int nx = t + 2;
            if (nx < nk) STAGE(cur == 0 ? 2 : cur - 1, nx << 6);
            COMPUTE(cur);
            if (t + 1 < nk) {
                if (nx < nk) asm volatile("s_waitcnt vmcnt(6)" ::: "memory");
                else         asm volatile("s_waitcnt vmcnt(0)" ::: "memory");
                __builtin_amdgcn_s_barrier();
            }
            cur = (cur == 2) ? 0 : cur + 1;
        }
    } else {
        STAGE(0, 0);
        __syncthreads();   // vmcnt(0) drain: buf0 ready
        int cur = 0;
        for (int t = 0; t < nk; ++t) {
            if (t + 1 < nk) STAGE(cur ^ 1, (t + 1) << (BK64 ? 6 : 5));
            COMPUTE(cur);
            __syncthreads();   // drains vmcnt(0): next buffer staged
            cur ^= 1;
        }
    }

#pragma unroll
    for (int j = 0; j < 4; ++j) {
        int col = n0 + wc * 64 + j * 16 + ln;
        float bj = bj4[j];
#pragma unroll
        for (int i = 0; i < MI; ++i) {
            int rb = m0 + wr * MW + i * 16 + rg * 4;
            if constexpr (VTOUT == 1) {
                int bq = rb >> 9, s = rb & 511;
                int hh = col >> 6, dk = col & 63;
                f16x4 o;
#pragma unroll
                for (int r = 0; r < 4; ++r) o[r] = (f16)(acc[i][j][r] + bj);
                *(f16x4*)(Ch + (((size_t)(bq * 8 + hh) * 64 + dk) << 9) + s) = o;
            } else if constexpr (VTOUT == 2) {
                if (n0 < 512) {       // qh half (block-uniform branch)
#pragma unroll
                    for (int r = 0; r < 4; ++r)
                        Ch[(size_t)(rb + r) * 512 + col] = (f16)(acc[i][j][r] + bj);
                } else {              // vt half
                    f16* Cv = (f16*)C;
                    int colv = col - 512;
                    int bq = rb >> 9, s = rb & 511;
                    int hh = colv >> 6, dk = colv & 63;
                    f16x4 o;
#pragma unroll
                    for (int r = 0; r < 4; ++r) o[r] = (f16)(acc[i][j][r] + bj);
                    *(f16x4*)(Cv + (((size_t)(bq * 8 + hh) * 64 + dk) << 9) + s) = o;
                }
            } else if constexpr (VTOUT == 3) {
                if (half == 0) {      // qh
#pragma unroll
                    for (int r = 0; r < 4; ++r)
                        Ch[(size_t)(rb + r) * 512 + col] = (f16)(acc[i][j][r] + bj);
                } else {              // vt
                    int bq = rb >> 9, s = rb & 511;
                    int hh = col >> 6, dk = col & 63;
                    f16x4 o;
#pragma unroll
                    for (int r = 0; r < 4; ++r) o[r] = (f16)(acc[i][j][r] + bj);
                    *(f16x4*)(Ch2 + (((size_t)(bq * 8 + hh) * 64 + dk) << 9) + s) = o;
                }
            } else {
#pragma unroll
                for (int r = 0; r < 4; ++r) {
                    float v = acc[i][j][r] + bj;
                    if (RELU) v = fmaxf(v, 0.f);
                    if (OUT16) Ch[(size_t)(rb + r) * N + col] = (f16)v;
                    else       C [(size_t)(rb + r) * N + col] = v;
                }
            }
        }
    }
}

// ---------------------------------------------------------------------------
// AKT attention body, specialized on JTC. (Unchanged — frozen while its
// wall time swings with frozen counters; see r9/r11 notes.)
// ---------------------------------------------------------------------------
template <int JTC>
__device__ __forceinline__ void attn_body(
    float (*Sc)[516], f16* Ph, const f16* Qbase, const f16* vbase, f16* ob,
    f16x8 aq0, f16x8 aq1, float g,
    int w, int lane, int ln, int rg, int i0, int maskflag)
{
    // ---- Phase 1: scores, 16-col unit granularity across waves ----------
#pragma unroll
    for (int ui = 0; ui < JTC; ++ui) {
        int u = w + ui * 4;
        const f16* kb = Qbase + (size_t)(u * 16 + ln) * Dm + rg * 8;
        f16x8 b0 = *(const f16x8*)(kb);
        f16x8 b1 = *(const f16x8*)(kb + 32);
        f32x4 c = {};
        c = __builtin_amdgcn_mfma_f32_16x16x32_f16(aq0, b0, c, 0, 0, 0);
        c = __builtin_amdgcn_mfma_f32_16x16x32_f16(aq1, b1, c, 0, 0, 0);
#pragma unroll
        for (int r = 0; r < 4; ++r)
            Sc[rg * 4 + r][u * 16 + ln] = c[r];
    }
    __syncthreads();

    int jbase = lane * JTC;
    int im = i0 + w * 4;

    // ---- loop A: vector-read scores -> regs, mask+scale, first exp-sums -
    float ss[4][JTC];
    float run[4];
#pragma unroll
    for (int q = 0; q < 4; ++q) {
        const float* Srow = &Sc[w * 4 + q][0];
        if constexpr (JTC == 8) {
            float4 t0 = *(const float4*)(Srow + jbase);
            float4 t1 = *(const float4*)(Srow + jbase + 4);
            ss[q][0] = t0.x; ss[q][1] = t0.y; ss[q][2] = t0.z; ss[q][3] = t0.w;
            ss[q][4] = t1.x; ss[q][5] = t1.y; ss[q][6] = t1.z; ss[q][7] = t1.w;
        } else if constexpr (JTC == 4) {
            float4 t0 = *(const float4*)(Srow + jbase);
            ss[q][0] = t0.x; ss[q][1] = t0.y; ss[q][2] = t0.z; ss[q][3] = t0.w;
        } else {
#pragma unroll
            for (int k = 0; k < JTC; ++k) ss[q][k] = Srow[jbase + k];
        }
        int jmax = maskflag ? (im + q) : (im + q - 1);
        float acc = 0.f;
#pragma unroll
        for (int k = 0; k < JTC; ++k) {
            int j = jbase + k;
            float s = (j <= jmax) ? ss[q][k] * 0.125f : NEGV;
            ss[q][k] = s;
            acc += __expf(s);              // exp(-1e32) = 0 for masked
        }
        run[q] = acc;
    }
    // 4 interleaved inclusive scans across lanes (j-ordered)
    float sl[4] = { run[0], run[1], run[2], run[3] };
#pragma unroll
    for (int off = 1; off < 64; off <<= 1) {
        float n0 = __shfl_up(sl[0], off);
        float n1 = __shfl_up(sl[1], off);
        float n2 = __shfl_up(sl[2], off);
        float n3 = __shfl_up(sl[3], off);
        if (lane >= off) { sl[0] += n0; sl[1] += n1; sl[2] += n2; sl[3] += n3; }
    }

    // ---- loop B: LDS-free decay + second softmax (unnormalized) ---------
    float Z2[4];
#pragma unroll
    for (int q = 0; q < 4; ++q) {
        float excl = sl[q] - run[q];
        float Z = __shfl(sl[q], 63);
        float inv = 1.f / Z;
        int i = im + q;
        float csum = 0.f, z2 = 0.f;
#pragma unroll
        for (int k = 0; k < JTC; ++k) {
            int j = jbase + k;
            float s = ss[q][k];
            csum += __expf(s);                       // inclusive cumsum
            float rem = (Z - excl - csum) * inv;     // disttot - distcum
            float pos = fabsf((float)(i - j));
            float dd = fmaxf(rem * pos, 0.f);        // fmax(NaN,0)=0 safe
            float te = __expf(sqrtf(dd) * g);
            te = fminf(fmaxf(te, 1e-5f), 1e5f);
            float pe2 = __expf(s * te);              // masked: -1e32*te -> 0
            ss[q][k] = pe2;
            z2 += pe2;
        }
        Z2[q] = z2;
    }
    // 4 interleaved sum reductions
#pragma unroll
    for (int off = 32; off >= 1; off >>= 1) {
        Z2[0] += __shfl_xor(Z2[0], off);
        Z2[1] += __shfl_xor(Z2[1], off);
        Z2[2] += __shfl_xor(Z2[2], off);
        Z2[3] += __shfl_xor(Z2[3], off);
    }
    __syncthreads();   // ALL waves' Sc reads done; Ph may now overwrite Sc

    // ---- write normalized P f16 into swizzled Ph ------------------------
#pragma unroll
    for (int q = 0; q < 4; ++q) {
        int r = w * 4 + q;
        float inv2 = 1.f / Z2[q];
        int zp = (maskflag == 0) && (im + q == 0);
        if constexpr (JTC == 8) {
            int slot = (lane & ~7) | ((lane & 7) ^ (r & 7));
            f16x8 o8;
#pragma unroll
            for (int k = 0; k < 8; ++k)
                o8[k] = (f16)(zp ? 0.f : ss[q][k] * inv2);
            *(f16x8*)(Ph + r * 512 + slot * 8) = o8;
        } else if constexpr (JTC == 4) {
            int cj = lane >> 1;
            int slot = (cj & ~7) | ((cj & 7) ^ (r & 7));
            f16x4 o4;
#pragma unroll
            for (int k = 0; k < 4; ++k)
                o4[k] = (f16)(zp ? 0.f : ss[q][k] * inv2);
            *(f16x4*)(Ph + r * 512 + slot * 8 + (lane & 1) * 4) = o4;
        } else {
#pragma unroll
            for (int k = 0; k < JTC; ++k) {
                int j = jbase + k;
                int cj = j >> 3;
                int slot = (cj & ~7) | ((cj & 7) ^ (r & 7));
                Ph[r * 512 + slot * 8 + (j & 7)] =
                    (f16)(zp ? 0.f : ss[q][k] * inv2);
            }
        }
    }
    __syncthreads();

    // ---- Phase 3: O = P @ V, dual accumulator ---------------------------
    f32x4 oa0 = {}, oa1 = {};
#pragma unroll
    for (int f = 0; f < 2 * JTC; ++f) {
        f16x8 bv = *(const f16x8*)(vbase + (f >> 1) * 64 + (f & 1) * 32);
        int c = (f >> 1) * 8 + (f & 1) * 4 + rg;
        int slot = (c & ~7) | ((c & 7) ^ (ln & 7));
        f16x8 ap = *(const f16x8*)(Ph + ln * 512 + slot * 8);
        if (f & 1) oa1 = __builtin_amdgcn_mfma_f32_16x16x32_f16(ap, bv, oa1, 0, 0, 0);
        else       oa0 = __builtin_amdgcn_mfma_f32_16x16x32_f16(ap, bv, oa0, 0, 0, 0);
    }
    f32x4 oa = oa0 + oa1;
#pragma unroll
    for (int r = 0; r < 4; ++r)
        ob[(size_t)r * Dm] = (f16)oa[r];
}

// ---------------------------------------------------------------------------
// AKT attention. One block per (b, h, 16-row i-tile), 4 waves.
// XCD-chunked swizzle (proven). Heavy-first LPT order.
// ---------------------------------------------------------------------------
__global__ __launch_bounds__(256, 4) void k_attn(
    const f16* __restrict__ Qh, const f16* __restrict__ VT,
    f16* __restrict__ O, const float* __restrict__ gam, int maskflag)
{
    __shared__ float Sc[16][516];
    f16* Ph = (f16*)Sc;          // 16KB alias, safe after post-read barrier

    int tid = threadIdx.x;
    int w = tid >> 6, lane = tid & 63;
    int ln = lane & 15, rg = lane >> 4;

    // XCD-chunked bijective remap (4096 blocks, 8 XCDs, 512 each)
    int bid = blockIdx.x;
    int lbid = (bid & 7) * 512 + (bid >> 3);
    int tile = 31 - (lbid & 31);        // heavy-first within each bh
    int bh = lbid >> 5;
    int b = bh >> 3, h = bh & 7;
    int i0 = tile * 16;
    int jtc = (tile >> 2) + 1;          // valid j-tiles (64 cols each)

    const f16* Qbase = Qh + ((size_t)b * Sl) * Dm + h * DKh;
    const f16* vbase = VT + ((size_t)bh * 64 + w * 16 + ln) * 512 + rg * 8;
    f16* ob = O + ((size_t)b * Sl + i0 + rg * 4) * Dm + h * DKh + w * 16 + ln;

    float gm = gam[h];
    float g = -((gm > 20.f) ? gm : log1pf(__expf(gm)));   // -softplus(gamma)

    // A-frags: Q rows i0..i0+15, reused across units
    f16x8 aq0 = *(const f16x8*)(Qbase + (size_t)(i0 + ln) * Dm + rg * 8);
    f16x8 aq1 = *(const f16x8*)(Qbase + (size_t)(i0 + ln) * Dm + 32 + rg * 8);

    switch (jtc) {
    case 1: attn_body<1>(Sc, Ph, Qbase, vbase, ob, aq0, aq1, g, w, lane, ln, rg, i0, maskflag); break;
    case 2: attn_body<2>(Sc, Ph, Qbase, vbase, ob, aq0, aq1, g, w, lane, ln, rg, i0, maskflag); break;
    case 3: attn_body<3>(Sc, Ph, Qbase, vbase, ob, aq0, aq1, g, w, lane, ln, rg, i0, maskflag); break;
    case 4: attn_body<4>(Sc, Ph, Qbase, vbase, ob, aq0, aq1, g, w, lane, ln, rg, i0, maskflag); break;
    case 5: attn_body<5>(Sc, Ph, Qbase, vbase, ob, aq0, aq1, g, w, lane, ln, rg, i0, maskflag); break;
    case 6: attn_body<6>(Sc, Ph, Qbase, vbase, ob, aq0, aq1, g, w, lane, ln, rg, i0, maskflag); break;
    case 7: attn_body<7>(Sc, Ph, Qbase, vbase, ob, aq0, aq1, g, w, lane, ln, rg, i0, maskflag); break;
    default: attn_body<8>(Sc, Ph, Qbase, vbase, ob, aq0, aq1, g, w, lane, ln, rg, i0, maskflag); break;
    }
}

// ---------------------------------------------------------------------------
// Residual + LayerNorm: Out = LN(Xn_f16 + Rr)*g + b, dual f32+f16 output.
// ---------------------------------------------------------------------------
__global__ __launch_bounds__(256) void k_ln(
    const f16* __restrict__ Xn, const float* __restrict__ Rr,
    const float* __restrict__ gw, const float* __restrict__ bw,
    float* __restrict__ Out, f16* __restrict__ Outh)
{
    int tid = threadIdx.x;
    int w = tid >> 6, lane = tid & 63;
    int row = blockIdx.x * 4 + w;
    const f16* xr = Xn + (size_t)row * Dm;
    const float* rr = Rr + (size_t)row * Dm;
    int c0 = lane * 4, c1 = 256 + lane * 4;
    f16x4 xa = *(const f16x4*)(xr + c0);
    f16x4 xb = *(const f16x4*)(xr + c1);
    float4 ra = *(const float4*)(rr + c0);
    float4 rb = *(const float4*)(rr + c1);
    float4 va, vb;
    va.x = (float)xa[0] + ra.x; va.y = (float)xa[1] + ra.y;
    va.z = (float)xa[2] + ra.z; va.w = (float)xa[3] + ra.w;
    vb.x = (float)xb[0] + rb.x; vb.y = (float)xb[1] + rb.y;
    vb.z = (float)xb[2] + rb.z; vb.w = (float)xb[3] + rb.w;
    float sum = va.x + va.y + va.z + va.w + vb.x + vb.y + vb.z + vb.w;
#pragma unroll
    for (int off = 32; off >= 1; off >>= 1) sum += __shfl_xor(sum, off);
    float mu = sum * (1.f / 512.f);
    float var = 0.f;
    {
        float d;
        d = va.x - mu; var += d * d;  d = va.y - mu; var += d * d;
        d = va.z - mu; var += d * d;  d = va.w - mu; var += d * d;
        d = vb.x - mu; var += d * d;  d = vb.y - mu; var += d * d;
        d = vb.z - mu; var += d * d;  d = vb.w - mu; var += d * d;
    }
#pragma unroll
    for (int off = 32; off >= 1; off >>= 1) var += __shfl_xor(var, off);
    float rs = rsqrtf(var * (1.f / 512.f) + 1e-5f);
    float4 ga = *(const float4*)(gw + c0);
    float4 gb = *(const float4*)(gw + c1);
    float4 ba = *(const float4*)(bw + c0);
    float4 bb = *(const float4*)(bw + c1);
    float4 oa, ob;
    oa.x = (va.x - mu) * rs * ga.x + ba.x;  oa.y = (va.y - mu) * rs * ga.y + ba.y;
    oa.z = (va.z - mu) * rs * ga.z + ba.z;  oa.w = (va.w - mu) * rs * ga.w + ba.w;
    ob.x = (vb.x - mu) * rs * gb.x + bb.x;  ob.y = (vb.y - mu) * rs * gb.y + bb.y;
    ob.z = (vb.z - mu) * rs * gb.z + bb.z;  ob.w = (vb.w - mu) * rs * gb.w + bb.w;
    float* orow = Out + (size_t)row * Dm;
    f16* ohrow = Outh + (size_t)row * Dm;
    *(float4*)(orow + c0) = oa;
    *(float4*)(orow + c1) = ob;
    f16x4 ha = { (f16)oa.x, (f16)oa.y, (f16)oa.z, (f16)oa.w };
    f16x4 hb = { (f16)ob.x, (f16)ob.y, (f16)ob.z, (f16)ob.w };
    *(f16x4*)(ohrow + c0) = ha;
    *(f16x4*)(ohrow + c1) = hb;
}

// ---------------------------------------------------------------------------
extern "C" void kernel_launch(void* const* d_in, const int* in_sizes, int n_in,
                              void* d_out, int out_size, void* d_ws, size_t ws_size,
                              hipStream_t stream)
{
    const float* q_emb  = (const float*)d_in[0];
    const float* qa_emb = (const float*)d_in[1];
    const float* Wk  = (const float*)d_in[3];
    const float* bk  = (const float*)d_in[4];
    const float* Wv  = (const float*)d_in[5];
    const float* bv  = (const float*)d_in[6];
    const float* Wo  = (const float*)d_in[7];
    const float* bo  = (const float*)d_in[8];
    const float* gam = (const float*)d_in[9];
    const float* l1g = (const float*)d_in[10];
    const float* l1b = (const float*)d_in[11];
    const float* W1  = (const float*)d_in[12];
    const float* b1  = (const float*)d_in[13];
    const float* W2  = (const float*)d_in[14];
    const float* b2  = (const float*)d_in[15];
    const float* l2g = (const float*)d_in[16];
    const float* l2b = (const float*)d_in[17];
    float* outp = (float*)d_out;

    const size_t NE  = (size_t)MROWS * Dm;    // 4194304
    const size_t WDD = (size_t)Dm * Dm;
    const size_t WDF = (size_t)Dm * DFFn;
    const size_t WKV = 2 * WDD;               // concat KV slice [1024][512]

    float* xbuf = (float*)d_ws;               // NE f32 (residual stream x)
    float* ybuf = xbuf + NE;                  // NE f32 (residual stream y)
    float* t2   = ybuf + NE;                  // NE f32 region; f16 alias below
    f16* t2h = (f16*)t2;                      // f16 GEMM->LN intermediate
    f16* xh  = (f16*)(t2 + NE);               // NE
    f16* yh  = xh + NE;                       // NE
    f16* R   = yh + NE;                       // 4*NE f16 region
    f16* qh  = R;                             // q(=k) heads f16
    f16* vt  = R + 2 * NE;                    // v transposed per head (fused)
    f16* t1h = R + 3 * NE;                    // attention output f16
    f16* fbh = R;                             // FFN hidden (aliases R, 4*NE)
    f16* wkvh = R + 4 * NE;                   // concat KV weights [6][1024][512]
    f16* woh = wkvh + 6 * WKV;
    f16* w1h = woh + 6 * WDD;                 // slots 0,1,3,5
    f16* w2h = w1h + 4 * WDF;
    float* bkv = (float*)(w2h + 4 * WDF);     // [6][1024] f32

    // ---- single prep launch: weight convert + bias concat + f16 input conv
    PrepArgs pa;
    pa.Wk = Wk; pa.Wv = Wv; pa.Wo = Wo; pa.W1 = W1; pa.W2 = W2;
    pa.bk = bk; pa.bv = bv; pa.q_emb = q_emb; pa.qa_emb = qa_emb;
    pa.wkvh = wkvh; pa.woh = woh; pa.w1h = w1h; pa.w2h = w2h;
    pa.bkv = bkv; pa.xh = xh; pa.yh = yh;
    k_prep<<<21016, 256, 0, stream>>>(pa);

    // rIn: residual source for the FIRST LN of this layer.
    // finalOut: the LAST LN's f32 result goes to the output buffer.
    auto layer = [&](int l, int maskflag, float* Xq, f16* Xqh, f16* Xvh,
                     bool apply_pos, const float* rIn, float* finalOut) {
        if (Xqh == Xvh) {
            // fused KV projection: N=1024, 512 blocks (2/CU)
            k_gemm<0, 1, 2, 1, 128, 0><<<dim3(1024 / 128, MROWS / 128), 256, 0, stream>>>(
                Xqh, wkvh + (size_t)l * WKV, bkv + l * 1024, (float*)vt, qh,
                MROWS, 1024, Dm, nullptr, nullptr);
        } else {
            // DUAL: K-proj of Xqh and V-proj of Xvh in one 512-block launch
            k_gemm<0, 1, 3, 1, 128, 0><<<dim3(8, MROWS / 128), 256, 0, stream>>>(
                Xqh, wkvh + (size_t)l * WKV, bkv + l * 1024, nullptr, qh,
                MROWS, 512, Dm, Xvh, vt);
        }
        k_attn<<<Bsz * Hn * 32, 256, 0, stream>>>(qh, vt, t1h, gam + l * Hn, maskflag);
        // Wo GEMM: BM=64 DEEP (512 blocks, 2/CU, 3-buffer counted vmcnt)
        k_gemm<0, 1, 0, 1, 64, 1><<<dim3(Dm / 128, MROWS / 64), 256, 0, stream>>>(
            t1h, woh + (size_t)l * WDD, bo + l * Dm, nullptr, t2h,
            MROWS, Dm, Dm, nullptr, nullptr);
        if (apply_pos) {
            k_ln<<<MROWS / 4, 256, 0, stream>>>(t2h, rIn, l1g + l * Dm, l1b + l * Dm, Xq, Xqh);
            int sl = (l < 2) ? l : ((l + 1) >> 1);
            k_gemm<1, 1, 0, 0, 128, 0><<<dim3(DFFn / 128, MROWS / 128), 256, 0, stream>>>(
                Xqh, w1h + (size_t)sl * WDF, b1 + l * DFFn, nullptr, fbh,
                MROWS, DFFn, Dm, nullptr, nullptr);
            // FFN2: BM=64 DEEP, f16 output -> t2h
            k_gemm<0, 1, 0, 1, 64, 1><<<dim3(Dm / 128, MROWS / 64), 256, 0, stream>>>(
                fbh, w2h + (size_t)sl * WDF, b2 + l * Dm, nullptr, t2h,
                MROWS, Dm, DFFn, nullptr, nullptr);
            k_ln<<<MROWS / 4, 256, 0, stream>>>(t2h, Xq, l2g + l * Dm, l2b + l * Dm,
                                                finalOut ? finalOut : Xq, Xqh);
        } else {
            k_ln<<<MROWS / 4, 256, 0, stream>>>(t2h, rIn, l1g + l * Dm, l1b + l * Dm,
                                                finalOut ? finalOut : Xq, Xqh);
        }
    };

    const size_t NEo = NE;
    // blocks_1: self-attn on y, mask=1, FFN. Layer 1 is y's final write -> out+NE.
    layer(0, 1, ybuf, yh, yh, true, qa_emb, nullptr);
    layer(1, 1, ybuf, yh, yh, true, ybuf, outp + NEo);
    // blocks_2: (mask=1, no FFN) then (mask=0, values=y, FFN), twice.
    // Layer 5 is x's final write -> out.
    layer(2, 1, xbuf, xh, xh, false, q_emb, nullptr);
    layer(3, 0, xbuf, xh, yh, true, xbuf, nullptr);
    layer(4, 1, xbuf, xh, xh, false, xbuf, nullptr);
    layer(5, 0, xbuf, xh, yh, true, xbuf, outp);
}